// Round 9
// baseline (3235.112 us; speedup 1.0000x reference)
//
#include <hip/hip_runtime.h>

#define NN 50000
#define NE 800000
#define D 128
#define HE 32
#define HEADS 4
#define DEPTH 8
#define EPSV 1e-5f
#define SLOPE 0.01f
#define CHUNK 196  // 196*256 >= 50000

__device__ __forceinline__ float lrelu(float x) { return x > 0.f ? x : SLOPE * x; }

__device__ __forceinline__ float bf2f(unsigned short u) {
    union { float f; unsigned i; } c;
    c.i = ((unsigned)u) << 16;
    return c.f;
}
__device__ __forceinline__ unsigned short f2bf(float f) {
    union { float f; unsigned i; } c;
    c.f = f;
    unsigned r = c.i + 0x7FFFu + ((c.i >> 16) & 1u);  // RNE
    return (unsigned short)(r >> 16);
}
__device__ __forceinline__ unsigned pack2(float a, float b) {
    return (unsigned)f2bf(a) | ((unsigned)f2bf(b) << 16);
}
__device__ __forceinline__ void unpk2(unsigned u, float& a, float& b) {
    union { float f; unsigned i; } c;
    c.i = u << 16; a = c.f;
    c.i = u & 0xFFFF0000u; b = c.f;
}

// ---------- h init ----------
__global__ void k_init_h(const int* __restrict__ seq, const int* __restrict__ sec,
                         const float* __restrict__ Wseq, const float* __restrict__ Wsec,
                         float* __restrict__ h) {
    int n = blockIdx.x;
    int d = threadIdx.x;  // 128
    float v = (d < 96) ? Wseq[seq[n] * 96 + d] : Wsec[sec[n] * 32 + (d - 96)];
    h[(size_t)n * D + d] = v;
}

// ---------- CSR build ----------
__global__ void k_count(const int* __restrict__ dst, int* __restrict__ cnt) {
    int e = blockIdx.x * blockDim.x + threadIdx.x;
    if (e < NE) atomicAdd(&cnt[dst[e]], 1);
}

__global__ void k_bsum(const int* __restrict__ cnt, int* __restrict__ bsum) {
    __shared__ int sh[256];
    int b = blockIdx.x, tid = threadIdx.x;
    int idx = b * CHUNK + tid;
    int v = (tid < CHUNK && idx < NN) ? cnt[idx] : 0;
    sh[tid] = v;
    __syncthreads();
    for (int st = 128; st >= 1; st >>= 1) {
        if (tid < st) sh[tid] += sh[tid + st];
        __syncthreads();
    }
    if (tid == 0) bsum[b] = sh[0];
}

__global__ void k_bscan(const int* __restrict__ bsum, int* __restrict__ bscan,
                        int* __restrict__ indptr) {
    __shared__ int sh[256];
    int tid = threadIdx.x;
    int v = bsum[tid];
    sh[tid] = v;
    __syncthreads();
    for (int st = 1; st < 256; st <<= 1) {
        int t = (tid >= st) ? sh[tid - st] : 0;
        __syncthreads();
        sh[tid] += t;
        __syncthreads();
    }
    bscan[tid] = sh[tid] - v;  // exclusive
    if (tid == 255) indptr[NN] = sh[255];
}

__global__ void k_bwrite(const int* __restrict__ cnt, const int* __restrict__ bscan,
                         int* __restrict__ indptr) {
    __shared__ int sh[256];
    int b = blockIdx.x, tid = threadIdx.x;
    int idx = b * CHUNK + tid;
    int v = (tid < CHUNK && idx < NN) ? cnt[idx] : 0;
    sh[tid] = v;
    __syncthreads();
    for (int st = 1; st < 256; st <<= 1) {
        int t = (tid >= st) ? sh[tid - st] : 0;
        __syncthreads();
        sh[tid] += t;
        __syncthreads();
    }
    if (tid < CHUNK && idx < NN) indptr[idx] = bscan[b] + sh[tid] - v;
}

__global__ void k_scatter(const int* __restrict__ dst, const int* __restrict__ indptr,
                          int* __restrict__ cursor, int* __restrict__ esort) {
    int e = blockIdx.x * blockDim.x + threadIdx.x;
    if (e >= NE) return;
    int dn = dst[e];
    int pos = atomicAdd(&cursor[dn], 1);
    esort[indptr[dn] + pos] = e;
}

__global__ void k_permute(const int* __restrict__ esort, const int* __restrict__ src,
                          const int* __restrict__ dst, const float* __restrict__ edge_p,
                          int* __restrict__ src_s, int* __restrict__ dst_s,
                          float* __restrict__ ep_s) {
    int i = blockIdx.x * blockDim.x + threadIdx.x;
    if (i >= NE) return;
    int e = esort[i];
    src_s[i] = src[e];
    dst_s[i] = dst[e];
    ep_s[i] = edge_p[e];
}

// ---------- fused node kernel, W staged in LDS (double-buffered 8-row stages) ----------
template <int APPLY_BN>
__global__ __launch_bounds__(256) void k_node(
    const float* __restrict__ hin, const float* __restrict__ scsh,
    const float* __restrict__ Wn_, const float* __restrict__ bn_,
    const float* __restrict__ Wni_, const float* __restrict__ Wnj_,
    unsigned short* __restrict__ hp, float* __restrict__ ni, float* __restrict__ nj) {
    __shared__ float hs[64][132];
    __shared__ float wb[2][8][192];
    int tid = threadIdx.x;
    int n0 = blockIdx.x * 64;

    float4 wreg[2];
    int wf0 = tid, wf1 = tid + 256;
    auto wload = [&](int s) {
#pragma unroll
        for (int u = 0; u < 2; u++) {
            int f = (u == 0) ? wf0 : wf1;
            if (f < 384) {
                int rr = f / 48, c = (f % 48) * 4;
                int dd = s * 8 + rr;
                const float* sp;
                if (c < 128) sp = Wn_ + (size_t)dd * 128 + c;
                else if (c < 160) sp = Wni_ + (size_t)dd * 32 + (c - 128);
                else sp = Wnj_ + (size_t)dd * 32 + (c - 160);
                wreg[u] = *(const float4*)sp;
            }
        }
    };
    auto wstore = [&](int buf) {
#pragma unroll
        for (int u = 0; u < 2; u++) {
            int f = (u == 0) ? wf0 : wf1;
            if (f < 384) {
                int rr = f / 48, c = (f % 48) * 4;
                *(float4*)&wb[buf][rr][c] = wreg[u];
            }
        }
    };

    wload(0);
#pragma unroll
    for (int k = 0; k < 8; k++) {
        int f = tid + k * 256;
        int r = f >> 5, c4 = f & 31;
        int row = n0 + r;
        if (row >= NN) row = NN - 1;
        float4 v = *(const float4*)(hin + (size_t)row * D + c4 * 4);
        if (APPLY_BN) {
            float4 sc = *(const float4*)(scsh + c4 * 4);
            float4 sh = *(const float4*)(scsh + 128 + c4 * 4);
            v.x = lrelu(v.x * sc.x + sh.x);
            v.y = lrelu(v.y * sc.y + sh.y);
            v.z = lrelu(v.z * sc.z + sh.z);
            v.w = lrelu(v.w * sc.w + sh.w);
        }
        *(float4*)(&hs[r][c4 * 4]) = v;
    }
    wstore(0);
    __syncthreads();

    int rg = tid >> 4;  // 0..15
    int cg = tid & 15;  // 0..15
    int pcol = 128 + (cg & 7) * 4 + ((cg < 8) ? 0 : 32);
    float4 bA = *(const float4*)(bn_ + cg * 4);
    float4 bB = *(const float4*)(bn_ + 64 + cg * 4);
    float4 accA[4], accB[4], accC[4];
#pragma unroll
    for (int r = 0; r < 4; r++) {
        accA[r] = bA;
        accB[r] = bB;
        accC[r] = make_float4(0.f, 0.f, 0.f, 0.f);
    }

#define FMA4(acc_, hv_, w_)                                     \
    (acc_).x += (hv_) * (w_).x; (acc_).y += (hv_) * (w_).y;     \
    (acc_).z += (hv_) * (w_).z; (acc_).w += (hv_) * (w_).w;

    for (int s = 0; s < 16; s++) {
        int cur = s & 1;
        if (s < 15) wload(s + 1);
#pragma unroll
        for (int dd = 0; dd < 8; dd++) {
            int d = s * 8 + dd;
            float h0 = hs[rg * 4 + 0][d];
            float h1 = hs[rg * 4 + 1][d];
            float h2 = hs[rg * 4 + 2][d];
            float h3 = hs[rg * 4 + 3][d];
            float4 wv0 = *(const float4*)&wb[cur][dd][cg * 4];
            float4 wv1 = *(const float4*)&wb[cur][dd][64 + cg * 4];
            float4 wv2 = *(const float4*)&wb[cur][dd][pcol];
            FMA4(accA[0], h0, wv0) FMA4(accA[1], h1, wv0)
            FMA4(accA[2], h2, wv0) FMA4(accA[3], h3, wv0)
            FMA4(accB[0], h0, wv1) FMA4(accB[1], h1, wv1)
            FMA4(accB[2], h2, wv1) FMA4(accB[3], h3, wv1)
            FMA4(accC[0], h0, wv2) FMA4(accC[1], h1, wv2)
            FMA4(accC[2], h2, wv2) FMA4(accC[3], h3, wv2)
        }
        __syncthreads();
        if (s < 15) {
            wstore((s + 1) & 1);
            __syncthreads();
        }
    }

    float* projOut = (cg < 8) ? ni : nj;
    int pc = (cg & 7) * 4;
#pragma unroll
    for (int r = 0; r < 4; r++) {
        int row = n0 + rg * 4 + r;
        if (row < NN) {
            ushort4 pa = make_ushort4(f2bf(accA[r].x), f2bf(accA[r].y), f2bf(accA[r].z),
                                      f2bf(accA[r].w));
            ushort4 pb = make_ushort4(f2bf(accB[r].x), f2bf(accB[r].y), f2bf(accB[r].z),
                                      f2bf(accB[r].w));
            *(ushort4*)(hp + (size_t)row * D + cg * 4) = pa;
            *(ushort4*)(hp + (size_t)row * D + 64 + cg * 4) = pb;
            *(float4*)(projOut + (size_t)row * HE + pc) = accC[r];
        }
    }
}

// ---------- layer-0 edge kernel (heads=1, e = scalar edge_p) ----------
__global__ __launch_bounds__(256) void k_edge0(
    const float* __restrict__ ep_s, const int* __restrict__ src_s,
    const int* __restrict__ dst_s, const float* __restrict__ ni,
    const float* __restrict__ nj, const float* __restrict__ Wfij,
    const float* __restrict__ attn, const float* __restrict__ ebias,
    unsigned short* __restrict__ fout, float* __restrict__ logits) {
    __shared__ float sw[HE], sa[HE], se[HE];
    int tid = threadIdx.x;
    if (tid < HE) {
        sw[tid] = Wfij[tid];
        sa[tid] = attn[tid];
        se[tid] = ebias[tid];
    }
    __syncthreads();
    int i = blockIdx.x * blockDim.x + tid;
    if (i >= NE) return;
    int sn = src_s[i], dn = dst_s[i];
    float p = ep_s[i];
    const float4* niv = (const float4*)(ni + (size_t)sn * HE);
    const float4* njv = (const float4*)(nj + (size_t)dn * HE);
    float acc[HE];
#pragma unroll
    for (int j = 0; j < 8; j++) {
        float4 a = niv[j];
        float4 b = njv[j];
        acc[4 * j + 0] = se[4 * j + 0] + p * sw[4 * j + 0] + a.x + b.x;
        acc[4 * j + 1] = se[4 * j + 1] + p * sw[4 * j + 1] + a.y + b.y;
        acc[4 * j + 2] = se[4 * j + 2] + p * sw[4 * j + 2] + a.z + b.z;
        acc[4 * j + 3] = se[4 * j + 3] + p * sw[4 * j + 3] + a.w + b.w;
    }
    float lg = 0.f;
#pragma unroll
    for (int k = 0; k < HE; k++) {
        acc[k] = lrelu(acc[k]);
        lg += acc[k] * sa[k];
    }
    uint4* fo = (uint4*)(fout + (size_t)i * HE);
#pragma unroll
    for (int j = 0; j < 4; j++) {
        uint4 v;
        v.x = pack2(acc[8 * j + 0], acc[8 * j + 1]);
        v.y = pack2(acc[8 * j + 2], acc[8 * j + 3]);
        v.z = pack2(acc[8 * j + 4], acc[8 * j + 5]);
        v.w = pack2(acc[8 * j + 6], acc[8 * j + 7]);
        fo[j] = v;
    }
    logits[i] = lg;
}

// ---------- deep edge kernel: 2 edges/thread, plane-major logits ----------
template <int FIRST, int LAST>
__global__ __launch_bounds__(256) void k_edgeB(
    const unsigned short* __restrict__ e_in, const int* __restrict__ src_s,
    const int* __restrict__ dst_s, const float* __restrict__ ni,
    const float* __restrict__ nj, const float* __restrict__ Wfij,
    const float* __restrict__ attn, const float* __restrict__ ebias,
    const float* __restrict__ scsh,  // [256..287]=scaleE, [288..319]=shiftE (prev layer)
    unsigned short* __restrict__ fout, float* __restrict__ logits) {
    int tid = threadIdx.x;
    int i0 = blockIdx.x * 512 + tid;
    if (i0 >= NE) return;
    int i1 = i0 + 256;
    bool v1 = i1 < NE;
    int sn0 = src_s[i0], dn0 = dst_s[i0];
    int sn1 = v1 ? src_s[i1] : sn0;
    int dn1 = v1 ? dst_s[i1] : dn0;
    const float4* ni0 = (const float4*)(ni + (size_t)sn0 * HE);
    const float4* nj0 = (const float4*)(nj + (size_t)dn0 * HE);
    const float4* ni1 = (const float4*)(ni + (size_t)sn1 * HE);
    const float4* nj1 = (const float4*)(nj + (size_t)dn1 * HE);
    float acc0[HE], acc1[HE];
#pragma unroll
    for (int j = 0; j < 8; j++) {
        float4 a0 = ni0[j], b0 = nj0[j];
        float4 a1 = ni1[j], b1 = nj1[j];
        float e0 = ebias[4 * j + 0], e1 = ebias[4 * j + 1];
        float e2 = ebias[4 * j + 2], e3 = ebias[4 * j + 3];
        acc0[4 * j + 0] = e0 + a0.x + b0.x;
        acc0[4 * j + 1] = e1 + a0.y + b0.y;
        acc0[4 * j + 2] = e2 + a0.z + b0.z;
        acc0[4 * j + 3] = e3 + a0.w + b0.w;
        acc1[4 * j + 0] = e0 + a1.x + b1.x;
        acc1[4 * j + 1] = e1 + a1.y + b1.y;
        acc1[4 * j + 2] = e2 + a1.z + b1.z;
        acc1[4 * j + 3] = e3 + a1.w + b1.w;
    }
    const uint4* ein0 = (const uint4*)(e_in + (size_t)i0 * HE);
    const uint4* ein1 = (const uint4*)(e_in + (size_t)i1 * HE);
#pragma unroll
    for (int j = 0; j < 4; j++) {
        uint4 ev0 = ein0[j];
        uint4 ev1 = v1 ? ein1[j] : ev0;
        float ec0[8], ec1[8];
        unpk2(ev0.x, ec0[0], ec0[1]); unpk2(ev0.y, ec0[2], ec0[3]);
        unpk2(ev0.z, ec0[4], ec0[5]); unpk2(ev0.w, ec0[6], ec0[7]);
        unpk2(ev1.x, ec1[0], ec1[1]); unpk2(ev1.y, ec1[2], ec1[3]);
        unpk2(ev1.z, ec1[4], ec1[5]); unpk2(ev1.w, ec1[6], ec1[7]);
#pragma unroll
        for (int c = 0; c < 8; c++) {
            int de = 8 * j + c;
            float x0 = ec0[c], x1 = ec1[c];
            if (!FIRST) {
                float sc = scsh[256 + de], sh = scsh[288 + de];
                x0 = lrelu(x0 * sc + sh);
                x1 = lrelu(x1 * sc + sh);
            }
            const float* wr = Wfij + (size_t)de * HE;
#pragma unroll
            for (int k = 0; k < HE; k++) {
                float w = wr[k];
                acc0[k] += x0 * w;
                acc1[k] += x1 * w;
            }
        }
    }
#pragma unroll
    for (int k = 0; k < HE; k++) {
        acc0[k] = lrelu(acc0[k]);
        acc1[k] = lrelu(acc1[k]);
    }
    if (!LAST) {
        uint4* fo0 = (uint4*)(fout + (size_t)i0 * HE);
#pragma unroll
        for (int j = 0; j < 4; j++) {
            uint4 v;
            v.x = pack2(acc0[8 * j + 0], acc0[8 * j + 1]);
            v.y = pack2(acc0[8 * j + 2], acc0[8 * j + 3]);
            v.z = pack2(acc0[8 * j + 4], acc0[8 * j + 5]);
            v.w = pack2(acc0[8 * j + 6], acc0[8 * j + 7]);
            fo0[j] = v;
        }
        if (v1) {
            uint4* fo1 = (uint4*)(fout + (size_t)i1 * HE);
#pragma unroll
            for (int j = 0; j < 4; j++) {
                uint4 v;
                v.x = pack2(acc1[8 * j + 0], acc1[8 * j + 1]);
                v.y = pack2(acc1[8 * j + 2], acc1[8 * j + 3]);
                v.z = pack2(acc1[8 * j + 4], acc1[8 * j + 5]);
                v.w = pack2(acc1[8 * j + 6], acc1[8 * j + 7]);
                fo1[j] = v;
            }
        }
    }
#pragma unroll
    for (int hh = 0; hh < HEADS; hh++) {
        float s0 = 0.f, s1 = 0.f;
#pragma unroll
        for (int j = 0; j < 8; j++) {
            float av = attn[hh * 8 + j];
            s0 += acc0[hh * 8 + j] * av;
            s1 += acc1[hh * 8 + j] * av;
        }
        logits[(size_t)hh * NE + i0] = s0;
        if (v1) logits[(size_t)hh * NE + i1] = s1;
    }
}

// ---------- segment softmax, plane-major logits [H][NE], in-place ----------
template <int H>
__global__ void k_softmax(const int* __restrict__ indptr, float* __restrict__ logits) {
    long t = (long)blockIdx.x * blockDim.x + threadIdx.x;
    if (t >= (long)NN * H) return;
    int n = (int)(t % NN);
    int hh = (int)(t / NN);
    float* lp = logits + (size_t)hh * NE;
    int b = indptr[n], e = indptr[n + 1];
    if (b == e) return;
    float m = -1e30f;
    for (int i = b; i < e; i++) m = fmaxf(m, lp[i]);
    float s = 0.f;
    for (int i = b; i < e; i++) {
        float z = __expf(lp[i] - m);
        lp[i] = z;
        s += z;
    }
    float inv = 1.f / s;
    for (int i = b; i < e; i++) lp[i] *= inv;
}

// ---------- aggregate: wave per node, 2 cols per lane, plane-major a ----------
template <int H>
__global__ __launch_bounds__(256) void k_aggregate(const int* __restrict__ indptr,
                                                   const int* __restrict__ src_s,
                                                   const float* __restrict__ a,
                                                   const unsigned short* __restrict__ hp,
                                                   float* __restrict__ hacc) {
    int n = blockIdx.x * 4 + (threadIdx.x >> 6);
    if (n >= NN) return;
    int lane = threadIdx.x & 63;
    int c2 = lane * 2;  // cols c2, c2+1
    int b = indptr[n], e = indptr[n + 1];
    int hh = (H == 1) ? 0 : (c2 >> 5);
    const float* ap = a + (size_t)hh * NE;
    float acc0 = 0.f, acc1 = 0.f;
#pragma unroll 4
    for (int i = b; i < e; i++) {
        float w = ap[i];
        unsigned u = *(const unsigned*)(hp + (size_t)src_s[i] * D + c2);
        float x0, x1;
        unpk2(u, x0, x1);
        acc0 += w * x0;
        acc1 += w * x1;
    }
    *(float2*)(hacc + (size_t)n * D + c2) = make_float2(acc0, acc1);
}

// ---------- batchnorm stats (f32 input, C=128) ----------
__global__ __launch_bounds__(256) void k_bnstatsH(const float* __restrict__ x,
                                                  float* __restrict__ sums) {
    __shared__ float sh[512];
    int tid = threadIdx.x;
    int d = tid & 127;
    int r0 = tid >> 7;
    float s = 0.f, s2 = 0.f;
    for (long r = (long)blockIdx.x * 2 + r0; r < NN; r += (long)gridDim.x * 2) {
        float v = x[r * D + d];
        s += v;
        s2 += v * v;
    }
    sh[tid] = s;
    sh[256 + tid] = s2;
    __syncthreads();
    if (tid < 128) {
        sh[tid] += sh[tid + 128];
        sh[256 + tid] += sh[256 + tid + 128];
    }
    __syncthreads();
    if (tid < 128) {
        atomicAdd(&sums[d], sh[tid]);
        atomicAdd(&sums[128 + d], sh[256 + tid]);
    }
}

// ---------- batchnorm stats (bf16 input, C=32) ----------
__global__ __launch_bounds__(256) void k_bnstatsE(const unsigned short* __restrict__ x,
                                                  float* __restrict__ sums) {
    __shared__ float sh[512];
    int tid = threadIdx.x;
    int d = tid & 31;
    int r0 = tid >> 5;
    float s = 0.f, s2 = 0.f;
    for (long r = (long)blockIdx.x * 8 + r0; r < NE; r += (long)gridDim.x * 8) {
        float v = bf2f(x[r * HE + d]);
        s += v;
        s2 += v * v;
    }
    sh[tid] = s;
    sh[256 + tid] = s2;
    __syncthreads();
    for (int st = 128; st >= 32; st >>= 1) {
        if (tid < st) {
            sh[tid] += sh[tid + st];
            sh[256 + tid] += sh[256 + tid + st];
        }
        __syncthreads();
    }
    if (tid < 32) {
        atomicAdd(&sums[d], sh[tid]);
        atomicAdd(&sums[32 + d], sh[256 + tid]);
    }
}

// ---------- BN scale/shift prep ----------
__global__ void k_bnprep(const float* __restrict__ sumsH, const float* __restrict__ gH,
                         const float* __restrict__ bH, const float* __restrict__ sumsE,
                         const float* __restrict__ gE, const float* __restrict__ bE,
                         float* __restrict__ scsh, int doE) {
    int t = threadIdx.x;  // 160
    if (t < 128) {
        float mu = sumsH[t] * (1.f / NN);
        float var = sumsH[128 + t] * (1.f / NN) - mu * mu;
        float sc = rsqrtf(var + EPSV) * gH[t];
        scsh[t] = sc;
        scsh[128 + t] = bH[t] - mu * sc;
    } else if (doE) {
        int k = t - 128;
        float mu = sumsE[k] * (1.f / NE);
        float var = sumsE[32 + k] * (1.f / NE) - mu * mu;
        float sc = rsqrtf(var + EPSV) * gE[k];
        scsh[256 + k] = sc;
        scsh[288 + k] = bE[k] - mu * sc;
    }
}

// ---------- out = lrelu(BN(h)) @ Wfc + bfc ----------
__global__ void k_out(const float* __restrict__ h, const float* __restrict__ scsh,
                      const float* __restrict__ Wfc, const float* __restrict__ bfc,
                      float* __restrict__ out) {
    int n = blockIdx.x * blockDim.x + threadIdx.x;
    if (n >= NN) return;
    const float* hr = h + (size_t)n * D;
    float s = bfc[0];
    for (int d = 0; d < D; d++) {
        float v = lrelu(hr[d] * scsh[d] + scsh[128 + d]);
        s += v * Wfc[d];
    }
    out[n] = s;
}

extern "C" void kernel_launch(void* const* d_in, const int* in_sizes, int n_in,
                              void* d_out, int out_size, void* d_ws, size_t ws_size,
                              hipStream_t stream) {
    const int* seq = (const int*)d_in[0];
    const int* sec = (const int*)d_in[1];
    const float* edge_p = (const float*)d_in[2];
    const int* src = (const int*)d_in[3];
    const int* dst = (const int*)d_in[4];
    const float* Wseq = (const float*)d_in[5];
    const float* Wsec = (const float*)d_in[6];
    const float* W0_node = (const float*)d_in[7];
    const float* b0_node = (const float*)d_in[8];
    const float* W0_ni = (const float*)d_in[9];
    const float* W0_fij = (const float*)d_in[10];
    const float* W0_nj = (const float*)d_in[11];
    const float* attn0 = (const float*)d_in[12];
    const float* ebias0 = (const float*)d_in[13];
    const float* Wn = (const float*)d_in[14];
    const float* bn = (const float*)d_in[15];
    const float* Wni = (const float*)d_in[16];
    const float* Wfij = (const float*)d_in[17];
    const float* Wnj = (const float*)d_in[18];
    const float* attnB = (const float*)d_in[19];
    const float* ebiasB = (const float*)d_in[20];
    const float* gn = (const float*)d_in[21];
    const float* betan = (const float*)d_in[22];
    const float* ge = (const float*)d_in[23];
    const float* betae = (const float*)d_in[24];
    const float* Wfc = (const float*)d_in[25];
    const float* bfc = (const float*)d_in[26];

    char* p = (char*)d_ws;
    auto alloc = [&](size_t bytes) -> char* {
        char* r = p;
        p += (bytes + 255) & ~(size_t)255;
        return r;
    };
    float* hA = (float*)alloc((size_t)NN * D * 4);
    float* hB = (float*)alloc((size_t)NN * D * 4);
    unsigned short* hp = (unsigned short*)alloc((size_t)NN * D * 2);      // bf16
    unsigned short* ebuf = (unsigned short*)alloc((size_t)NE * HE * 2);   // bf16, in-place
    float* logits = (float*)alloc((size_t)NE * HEADS * 4);                // [H][NE] planes
    float* ni = (float*)alloc((size_t)NN * HE * 4);
    float* nj = (float*)alloc((size_t)NN * HE * 4);
    int* esort = (int*)alloc((size_t)NE * 4);
    int* src_s = (int*)alloc((size_t)NE * 4);
    int* dst_s = (int*)alloc((size_t)NE * 4);
    float* ep_s = (float*)alloc((size_t)NE * 4);
    int* cnt = (int*)alloc((size_t)NN * 4);
    int* cursor = (int*)alloc((size_t)NN * 4);
    int* indptr = (int*)alloc((size_t)(NN + 1) * 4);
    int* bsum = (int*)alloc(256 * 4);
    int* bscan = (int*)alloc(256 * 4);
    float* sums = (float*)alloc(384 * 4);
    float* sumsH = sums;
    float* sumsE = sums + 256;
    float* scsh0 = (float*)alloc(320 * 4);
    float* scsh1 = (float*)alloc(320 * 4);

    const int EB = (NE + 255) / 256;   // 3125
    const int EB2 = (NE + 511) / 512;  // 1563
    const int NB64 = (NN + 63) / 64;   // 782

    // CSR build + permuted edge arrays
    hipMemsetAsync(cnt, 0, (size_t)NN * 4, stream);
    hipMemsetAsync(cursor, 0, (size_t)NN * 4, stream);
    k_init_h<<<NN, 128, 0, stream>>>(seq, sec, Wseq, Wsec, hB);
    k_count<<<EB, 256, 0, stream>>>(dst, cnt);
    k_bsum<<<256, 256, 0, stream>>>(cnt, bsum);
    k_bscan<<<1, 256, 0, stream>>>(bsum, bscan, indptr);
    k_bwrite<<<256, 256, 0, stream>>>(cnt, bscan, indptr);
    k_scatter<<<EB, 256, 0, stream>>>(dst, indptr, cursor, esort);
    k_permute<<<EB, 256, 0, stream>>>(esort, src, dst, edge_p, src_s, dst_s, ep_s);

    // ---- layer 0 (heads = 1), no BN ----
    k_node<0><<<NB64, 256, 0, stream>>>(hB, scsh0, W0_node, b0_node, W0_ni, W0_nj, hp, ni, nj);
    k_edge0<<<EB, 256, 0, stream>>>(ep_s, src_s, dst_s, ni, nj, W0_fij, attn0, ebias0, ebuf,
                                    logits);
    k_softmax<1><<<(NN + 255) / 256, 256, 0, stream>>>(indptr, logits);
    k_aggregate<1><<<(NN + 3) / 4, 256, 0, stream>>>(indptr, src_s, logits, hp, hA);

    // ---- deep layers (input hA for l=0; ping-pong) ----
    for (int l = 0; l < DEPTH; l++) {
        const float* Wn_l = Wn + (size_t)l * D * D;
        const float* bn_l = bn + (size_t)l * D;
        const float* Wni_l = Wni + (size_t)l * D * HE;
        const float* Wfij_l = Wfij + (size_t)l * HE * HE;
        const float* Wnj_l = Wnj + (size_t)l * D * HE;
        const float* attn_l = attnB + (size_t)l * HE;
        const float* eb_l = ebiasB + (size_t)l * HE;
        float* scshPrev = (l & 1) ? scsh0 : scsh1;
        float* scshCur = (l & 1) ? scsh1 : scsh0;
        float* hIn = (l & 1) ? hB : hA;
        float* hOut = (l & 1) ? hA : hB;

        if (l == 0)
            k_node<0><<<NB64, 256, 0, stream>>>(hIn, scshPrev, Wn_l, bn_l, Wni_l, Wnj_l, hp,
                                                ni, nj);
        else
            k_node<1><<<NB64, 256, 0, stream>>>(hIn, scshPrev, Wn_l, bn_l, Wni_l, Wnj_l, hp,
                                                ni, nj);

        if (l == 0)
            k_edgeB<1, 0><<<EB2, 256, 0, stream>>>(ebuf, src_s, dst_s, ni, nj, Wfij_l, attn_l,
                                                   eb_l, scshPrev, ebuf, logits);
        else if (l == DEPTH - 1)
            k_edgeB<0, 1><<<EB2, 256, 0, stream>>>(ebuf, src_s, dst_s, ni, nj, Wfij_l, attn_l,
                                                   eb_l, scshPrev, ebuf, logits);
        else
            k_edgeB<0, 0><<<EB2, 256, 0, stream>>>(ebuf, src_s, dst_s, ni, nj, Wfij_l, attn_l,
                                                   eb_l, scshPrev, ebuf, logits);
        k_softmax<HEADS><<<(NN * HEADS + 255) / 256, 256, 0, stream>>>(indptr, logits);
        k_aggregate<HEADS><<<(NN + 3) / 4, 256, 0, stream>>>(indptr, src_s, logits, hp, hOut);

        hipMemsetAsync(sums, 0, 384 * 4, stream);
        k_bnstatsH<<<1024, 256, 0, stream>>>(hOut, sumsH);
        if (l < DEPTH - 1) k_bnstatsE<<<1024, 256, 0, stream>>>(ebuf, sumsE);
        k_bnprep<<<1, 160, 0, stream>>>(sumsH, gn + (size_t)l * D, betan + (size_t)l * D,
                                        sumsE, ge + (size_t)l * HE, betae + (size_t)l * HE,
                                        scshCur, l < DEPTH - 1 ? 1 : 0);
    }

    // final h is in hA (l=7 wrote hOut=hA); BN of layer 7 is in scsh1
    k_out<<<(NN + 255) / 256, 256, 0, stream>>>(hA, scsh1, Wfc, bfc, (float*)d_out);
}

// Round 11
// 3085.973 us; speedup vs baseline: 1.0483x; 1.0483x over previous
//
#include <hip/hip_runtime.h>

#define NN 50000
#define NE 800000
#define D 128
#define HE 32
#define HEADS 4
#define DEPTH 8
#define EPSV 1e-5f
#define SLOPE 0.01f
#define CHUNK 196  // 196*256 >= 50000
#define SB 256     // stat blocks (fixed, for deterministic reduce)

__device__ __forceinline__ float lrelu(float x) { return x > 0.f ? x : SLOPE * x; }

__device__ __forceinline__ float bf2f(unsigned short u) {
    union { float f; unsigned i; } c;
    c.i = ((unsigned)u) << 16;
    return c.f;
}
__device__ __forceinline__ unsigned short f2bf(float f) {
    union { float f; unsigned i; } c;
    c.f = f;
    unsigned r = c.i + 0x7FFFu + ((c.i >> 16) & 1u);  // RNE
    return (unsigned short)(r >> 16);
}
__device__ __forceinline__ unsigned pack2(float a, float b) {
    return (unsigned)f2bf(a) | ((unsigned)f2bf(b) << 16);
}
__device__ __forceinline__ void unpk2(unsigned u, float& a, float& b) {
    union { float f; unsigned i; } c;
    c.i = u << 16; a = c.f;
    c.i = u & 0xFFFF0000u; b = c.f;
}

// ---------- h init ----------
__global__ void k_init_h(const int* __restrict__ seq, const int* __restrict__ sec,
                         const float* __restrict__ Wseq, const float* __restrict__ Wsec,
                         float* __restrict__ h) {
    int n = blockIdx.x;
    int d = threadIdx.x;  // 128
    float v = (d < 96) ? Wseq[seq[n] * 96 + d] : Wsec[sec[n] * 32 + (d - 96)];
    h[(size_t)n * D + d] = v;
}

// ---------- CSR build ----------
__global__ void k_count(const int* __restrict__ dst, int* __restrict__ cnt) {
    int e = blockIdx.x * blockDim.x + threadIdx.x;
    if (e < NE) atomicAdd(&cnt[dst[e]], 1);
}

__global__ void k_bsum(const int* __restrict__ cnt, int* __restrict__ bsum) {
    __shared__ int sh[256];
    int b = blockIdx.x, tid = threadIdx.x;
    int idx = b * CHUNK + tid;
    int v = (tid < CHUNK && idx < NN) ? cnt[idx] : 0;
    sh[tid] = v;
    __syncthreads();
    for (int st = 128; st >= 1; st >>= 1) {
        if (tid < st) sh[tid] += sh[tid + st];
        __syncthreads();
    }
    if (tid == 0) bsum[b] = sh[0];
}

__global__ void k_bscan(const int* __restrict__ bsum, int* __restrict__ bscan,
                        int* __restrict__ indptr) {
    __shared__ int sh[256];
    int tid = threadIdx.x;
    int v = bsum[tid];
    sh[tid] = v;
    __syncthreads();
    for (int st = 1; st < 256; st <<= 1) {
        int t = (tid >= st) ? sh[tid - st] : 0;
        __syncthreads();
        sh[tid] += t;
        __syncthreads();
    }
    bscan[tid] = sh[tid] - v;  // exclusive
    if (tid == 255) indptr[NN] = sh[255];
}

__global__ void k_bwrite(const int* __restrict__ cnt, const int* __restrict__ bscan,
                         int* __restrict__ indptr) {
    __shared__ int sh[256];
    int b = blockIdx.x, tid = threadIdx.x;
    int idx = b * CHUNK + tid;
    int v = (tid < CHUNK && idx < NN) ? cnt[idx] : 0;
    sh[tid] = v;
    __syncthreads();
    for (int st = 1; st < 256; st <<= 1) {
        int t = (tid >= st) ? sh[tid - st] : 0;
        __syncthreads();
        sh[tid] += t;
        __syncthreads();
    }
    if (tid < CHUNK && idx < NN) indptr[idx] = bscan[b] + sh[tid] - v;
}

__global__ void k_scatter(const int* __restrict__ dst, const int* __restrict__ indptr,
                          int* __restrict__ cursor, int* __restrict__ esort) {
    int e = blockIdx.x * blockDim.x + threadIdx.x;
    if (e >= NE) return;
    int dn = dst[e];
    int pos = atomicAdd(&cursor[dn], 1);
    esort[indptr[dn] + pos] = e;
}

// ---------- deterministic segment order: sort each segment by edge id ----------
__global__ void k_sortseg(const int* __restrict__ indptr, int* __restrict__ esort) {
    int n = blockIdx.x * blockDim.x + threadIdx.x;
    if (n >= NN) return;
    int b = indptr[n], e = indptr[n + 1];
    for (int i = b + 1; i < e; i++) {
        int v = esort[i];
        int j = i - 1;
        while (j >= b && esort[j] > v) {
            esort[j + 1] = esort[j];
            j--;
        }
        esort[j + 1] = v;
    }
}

__global__ void k_permute(const int* __restrict__ esort, const int* __restrict__ src,
                          const int* __restrict__ dst, const float* __restrict__ edge_p,
                          int* __restrict__ src_s, int* __restrict__ dst_s,
                          float* __restrict__ ep_s) {
    int i = blockIdx.x * blockDim.x + threadIdx.x;
    if (i >= NE) return;
    int e = esort[i];
    src_s[i] = src[e];
    dst_s[i] = dst[e];
    ep_s[i] = edge_p[e];
}

// ---------- fused node kernel, W staged in LDS (double-buffered 8-row stages) ----------
template <int APPLY_BN>
__global__ __launch_bounds__(256) void k_node(
    const float* __restrict__ hin, const float* __restrict__ scsh,
    const float* __restrict__ Wn_, const float* __restrict__ bn_,
    const float* __restrict__ Wni_, const float* __restrict__ Wnj_,
    unsigned short* __restrict__ hp, float* __restrict__ ni, float* __restrict__ nj) {
    __shared__ float hs[64][132];
    __shared__ float wb[2][8][192];
    int tid = threadIdx.x;
    int n0 = blockIdx.x * 64;

    float4 wreg[2];
    int wf0 = tid, wf1 = tid + 256;
    auto wload = [&](int s) {
#pragma unroll
        for (int u = 0; u < 2; u++) {
            int f = (u == 0) ? wf0 : wf1;
            if (f < 384) {
                int rr = f / 48, c = (f % 48) * 4;
                int dd = s * 8 + rr;
                const float* sp;
                if (c < 128) sp = Wn_ + (size_t)dd * 128 + c;
                else if (c < 160) sp = Wni_ + (size_t)dd * 32 + (c - 128);
                else sp = Wnj_ + (size_t)dd * 32 + (c - 160);
                wreg[u] = *(const float4*)sp;
            }
        }
    };
    auto wstore = [&](int buf) {
#pragma unroll
        for (int u = 0; u < 2; u++) {
            int f = (u == 0) ? wf0 : wf1;
            if (f < 384) {
                int rr = f / 48, c = (f % 48) * 4;
                *(float4*)&wb[buf][rr][c] = wreg[u];
            }
        }
    };

    wload(0);
#pragma unroll
    for (int k = 0; k < 8; k++) {
        int f = tid + k * 256;
        int r = f >> 5, c4 = f & 31;
        int row = n0 + r;
        if (row >= NN) row = NN - 1;
        float4 v = *(const float4*)(hin + (size_t)row * D + c4 * 4);
        if (APPLY_BN) {
            float4 sc = *(const float4*)(scsh + c4 * 4);
            float4 sh = *(const float4*)(scsh + 128 + c4 * 4);
            v.x = lrelu(v.x * sc.x + sh.x);
            v.y = lrelu(v.y * sc.y + sh.y);
            v.z = lrelu(v.z * sc.z + sh.z);
            v.w = lrelu(v.w * sc.w + sh.w);
        }
        *(float4*)(&hs[r][c4 * 4]) = v;
    }
    wstore(0);
    __syncthreads();

    int rg = tid >> 4;  // 0..15
    int cg = tid & 15;  // 0..15
    int pcol = 128 + (cg & 7) * 4 + ((cg < 8) ? 0 : 32);
    float4 bA = *(const float4*)(bn_ + cg * 4);
    float4 bB = *(const float4*)(bn_ + 64 + cg * 4);
    float4 accA[4], accB[4], accC[4];
#pragma unroll
    for (int r = 0; r < 4; r++) {
        accA[r] = bA;
        accB[r] = bB;
        accC[r] = make_float4(0.f, 0.f, 0.f, 0.f);
    }

#define FMA4(acc_, hv_, w_)                                     \
    (acc_).x += (hv_) * (w_).x; (acc_).y += (hv_) * (w_).y;     \
    (acc_).z += (hv_) * (w_).z; (acc_).w += (hv_) * (w_).w;

    for (int s = 0; s < 16; s++) {
        int cur = s & 1;
        if (s < 15) wload(s + 1);
#pragma unroll
        for (int dd = 0; dd < 8; dd++) {
            int d = s * 8 + dd;
            float h0 = hs[rg * 4 + 0][d];
            float h1 = hs[rg * 4 + 1][d];
            float h2 = hs[rg * 4 + 2][d];
            float h3 = hs[rg * 4 + 3][d];
            float4 wv0 = *(const float4*)&wb[cur][dd][cg * 4];
            float4 wv1 = *(const float4*)&wb[cur][dd][64 + cg * 4];
            float4 wv2 = *(const float4*)&wb[cur][dd][pcol];
            FMA4(accA[0], h0, wv0) FMA4(accA[1], h1, wv0)
            FMA4(accA[2], h2, wv0) FMA4(accA[3], h3, wv0)
            FMA4(accB[0], h0, wv1) FMA4(accB[1], h1, wv1)
            FMA4(accB[2], h2, wv1) FMA4(accB[3], h3, wv1)
            FMA4(accC[0], h0, wv2) FMA4(accC[1], h1, wv2)
            FMA4(accC[2], h2, wv2) FMA4(accC[3], h3, wv2)
        }
        __syncthreads();
        if (s < 15) {
            wstore((s + 1) & 1);
            __syncthreads();
        }
    }

    float* projOut = (cg < 8) ? ni : nj;
    int pc = (cg & 7) * 4;
#pragma unroll
    for (int r = 0; r < 4; r++) {
        int row = n0 + rg * 4 + r;
        if (row < NN) {
            ushort4 pa = make_ushort4(f2bf(accA[r].x), f2bf(accA[r].y), f2bf(accA[r].z),
                                      f2bf(accA[r].w));
            ushort4 pb = make_ushort4(f2bf(accB[r].x), f2bf(accB[r].y), f2bf(accB[r].z),
                                      f2bf(accB[r].w));
            *(ushort4*)(hp + (size_t)row * D + cg * 4) = pa;
            *(ushort4*)(hp + (size_t)row * D + 64 + cg * 4) = pb;
            *(float4*)(projOut + (size_t)row * HE + pc) = accC[r];
        }
    }
}

// ---------- layer-0 edge kernel (heads=1, e = scalar edge_p) ----------
__global__ __launch_bounds__(256) void k_edge0(
    const float* __restrict__ ep_s, const int* __restrict__ src_s,
    const int* __restrict__ dst_s, const float* __restrict__ ni,
    const float* __restrict__ nj, const float* __restrict__ Wfij,
    const float* __restrict__ attn, const float* __restrict__ ebias,
    unsigned short* __restrict__ fout, float* __restrict__ logits) {
    __shared__ float sw[HE], sa[HE], se[HE];
    int tid = threadIdx.x;
    if (tid < HE) {
        sw[tid] = Wfij[tid];
        sa[tid] = attn[tid];
        se[tid] = ebias[tid];
    }
    __syncthreads();
    int i = blockIdx.x * blockDim.x + tid;
    if (i >= NE) return;
    int sn = src_s[i], dn = dst_s[i];
    float p = ep_s[i];
    const float4* niv = (const float4*)(ni + (size_t)sn * HE);
    const float4* njv = (const float4*)(nj + (size_t)dn * HE);
    float acc[HE];
#pragma unroll
    for (int j = 0; j < 8; j++) {
        float4 a = niv[j];
        float4 b = njv[j];
        acc[4 * j + 0] = se[4 * j + 0] + p * sw[4 * j + 0] + a.x + b.x;
        acc[4 * j + 1] = se[4 * j + 1] + p * sw[4 * j + 1] + a.y + b.y;
        acc[4 * j + 2] = se[4 * j + 2] + p * sw[4 * j + 2] + a.z + b.z;
        acc[4 * j + 3] = se[4 * j + 3] + p * sw[4 * j + 3] + a.w + b.w;
    }
    float lg = 0.f;
#pragma unroll
    for (int k = 0; k < HE; k++) {
        acc[k] = lrelu(acc[k]);
        lg += acc[k] * sa[k];
    }
    uint4* fo = (uint4*)(fout + (size_t)i * HE);
#pragma unroll
    for (int j = 0; j < 4; j++) {
        uint4 v;
        v.x = pack2(acc[8 * j + 0], acc[8 * j + 1]);
        v.y = pack2(acc[8 * j + 2], acc[8 * j + 3]);
        v.z = pack2(acc[8 * j + 4], acc[8 * j + 5]);
        v.w = pack2(acc[8 * j + 6], acc[8 * j + 7]);
        fo[j] = v;
    }
    logits[i] = lg;
}

// ---------- deep edge kernel (heads=4); 1 edge/thread, plane-major logits ----------
template <int FIRST, int LAST>
__global__ __launch_bounds__(256) void k_edgeB(
    const unsigned short* __restrict__ e_in, const int* __restrict__ src_s,
    const int* __restrict__ dst_s, const float* __restrict__ ni,
    const float* __restrict__ nj, const float* __restrict__ Wfij,
    const float* __restrict__ attn, const float* __restrict__ ebias,
    const float* __restrict__ scsh,  // [256..287]=scaleE, [288..319]=shiftE (prev layer)
    unsigned short* __restrict__ fout, float* __restrict__ logits) {
    int i = blockIdx.x * blockDim.x + threadIdx.x;
    if (i >= NE) return;
    int sn = src_s[i], dn = dst_s[i];
    const float4* niv = (const float4*)(ni + (size_t)sn * HE);
    const float4* njv = (const float4*)(nj + (size_t)dn * HE);
    float acc[HE];
#pragma unroll
    for (int j = 0; j < 8; j++) {
        float4 a = niv[j];
        float4 b = njv[j];
        acc[4 * j + 0] = ebias[4 * j + 0] + a.x + b.x;
        acc[4 * j + 1] = ebias[4 * j + 1] + a.y + b.y;
        acc[4 * j + 2] = ebias[4 * j + 2] + a.z + b.z;
        acc[4 * j + 3] = ebias[4 * j + 3] + a.w + b.w;
    }
    const uint4* ein4 = (const uint4*)(e_in + (size_t)i * HE);
#pragma unroll
    for (int j = 0; j < 4; j++) {
        uint4 ev = ein4[j];
        float ec[8];
        unpk2(ev.x, ec[0], ec[1]);
        unpk2(ev.y, ec[2], ec[3]);
        unpk2(ev.z, ec[4], ec[5]);
        unpk2(ev.w, ec[6], ec[7]);
#pragma unroll
        for (int c = 0; c < 8; c++) {
            int de = 8 * j + c;
            float x = ec[c];
            if (!FIRST) x = lrelu(x * scsh[256 + de] + scsh[288 + de]);
            const float* wr = Wfij + (size_t)de * HE;
#pragma unroll
            for (int k = 0; k < HE; k++) acc[k] += x * wr[k];
        }
    }
#pragma unroll
    for (int k = 0; k < HE; k++) acc[k] = lrelu(acc[k]);
    if (!LAST) {
        uint4* fo = (uint4*)(fout + (size_t)i * HE);
#pragma unroll
        for (int j = 0; j < 4; j++) {
            uint4 v;
            v.x = pack2(acc[8 * j + 0], acc[8 * j + 1]);
            v.y = pack2(acc[8 * j + 2], acc[8 * j + 3]);
            v.z = pack2(acc[8 * j + 4], acc[8 * j + 5]);
            v.w = pack2(acc[8 * j + 6], acc[8 * j + 7]);
            fo[j] = v;
        }
    }
#pragma unroll
    for (int hh = 0; hh < HEADS; hh++) {
        float s = 0.f;
#pragma unroll
        for (int j = 0; j < 8; j++) s += acc[hh * 8 + j] * attn[hh * 8 + j];
        logits[(size_t)hh * NE + i] = s;
    }
}

// ---------- segment softmax, plane-major logits [H][NE], in-place ----------
template <int H>
__global__ void k_softmax(const int* __restrict__ indptr, float* __restrict__ logits) {
    long t = (long)blockIdx.x * blockDim.x + threadIdx.x;
    if (t >= (long)NN * H) return;
    int n = (int)(t % NN);
    int hh = (int)(t / NN);
    float* lp = logits + (size_t)hh * NE;
    int b = indptr[n], e = indptr[n + 1];
    if (b == e) return;
    float m = -1e30f;
    for (int i = b; i < e; i++) m = fmaxf(m, lp[i]);
    float s = 0.f;
    for (int i = b; i < e; i++) {
        float z = __expf(lp[i] - m);
        lp[i] = z;
        s += z;
    }
    float inv = 1.f / s;
    for (int i = b; i < e; i++) lp[i] *= inv;
}

// ---------- aggregate: wave per node, 2 cols per lane, plane-major a ----------
template <int H>
__global__ __launch_bounds__(256) void k_aggregate(const int* __restrict__ indptr,
                                                   const int* __restrict__ src_s,
                                                   const float* __restrict__ a,
                                                   const unsigned short* __restrict__ hp,
                                                   float* __restrict__ hacc) {
    int n = blockIdx.x * 4 + (threadIdx.x >> 6);
    if (n >= NN) return;
    int lane = threadIdx.x & 63;
    int c2 = lane * 2;  // cols c2, c2+1
    int b = indptr[n], e = indptr[n + 1];
    int hh = (H == 1) ? 0 : (c2 >> 5);
    const float* ap = a + (size_t)hh * NE;
    float acc0 = 0.f, acc1 = 0.f;
#pragma unroll 4
    for (int i = b; i < e; i++) {
        float w = ap[i];
        unsigned u = *(const unsigned*)(hp + (size_t)src_s[i] * D + c2);
        float x0, x1;
        unpk2(u, x0, x1);
        acc0 += w * x0;
        acc1 += w * x1;
    }
    *(float2*)(hacc + (size_t)n * D + c2) = make_float2(acc0, acc1);
}

// ---------- batchnorm stats: deterministic per-block partials ----------
// partialH layout: [SB][256] = [block][0..127 sum | 128..255 sumsq]
__global__ __launch_bounds__(256) void k_bnstatsH(const float* __restrict__ x,
                                                  float* __restrict__ partialH) {
    __shared__ float sh[512];
    int tid = threadIdx.x;
    int d = tid & 127;
    int r0 = tid >> 7;
    float s = 0.f, s2 = 0.f;
    for (long r = (long)blockIdx.x * 2 + r0; r < NN; r += (long)SB * 2) {
        float v = x[r * D + d];
        s += v;
        s2 += v * v;
    }
    sh[tid] = s;
    sh[256 + tid] = s2;
    __syncthreads();
    if (tid < 128) {
        float su = sh[tid] + sh[tid + 128];
        float sq = sh[256 + tid] + sh[256 + tid + 128];
        partialH[(size_t)blockIdx.x * 256 + tid] = su;
        partialH[(size_t)blockIdx.x * 256 + 128 + tid] = sq;
    }
}

// partialE layout: [SB][64] = [block][0..31 sum | 32..63 sumsq]
__global__ __launch_bounds__(256) void k_bnstatsE(const unsigned short* __restrict__ x,
                                                  float* __restrict__ partialE) {
    __shared__ float sh[512];
    int tid = threadIdx.x;
    int d = tid & 31;
    int r0 = tid >> 5;
    float s = 0.f, s2 = 0.f;
    for (long r = (long)blockIdx.x * 8 + r0; r < NE; r += (long)SB * 8) {
        float v = bf2f(x[r * HE + d]);
        s += v;
        s2 += v * v;
    }
    sh[tid] = s;
    sh[256 + tid] = s2;
    __syncthreads();
    for (int st = 128; st >= 32; st >>= 1) {
        if (tid < st) {
            sh[tid] += sh[tid + st];
            sh[256 + tid] += sh[256 + tid + st];
        }
        __syncthreads();
    }
    if (tid < 32) {
        partialE[(size_t)blockIdx.x * 64 + tid] = sh[tid];
        partialE[(size_t)blockIdx.x * 64 + 32 + tid] = sh[256 + tid];
    }
}

// ---------- BN scale/shift prep: fixed-order reduce of partials ----------
__global__ void k_bnprep(const float* __restrict__ partialH, const float* __restrict__ gH,
                         const float* __restrict__ bH, const float* __restrict__ partialE,
                         const float* __restrict__ gE, const float* __restrict__ bE,
                         float* __restrict__ scsh, int doE) {
    int t = threadIdx.x;  // 160
    if (t < 128) {
        float s = 0.f, s2 = 0.f;
        for (int b = 0; b < SB; b++) {
            s += partialH[(size_t)b * 256 + t];
            s2 += partialH[(size_t)b * 256 + 128 + t];
        }
        float mu = s * (1.f / NN);
        float var = s2 * (1.f / NN) - mu * mu;
        float sc = rsqrtf(var + EPSV) * gH[t];
        scsh[t] = sc;
        scsh[128 + t] = bH[t] - mu * sc;
    } else if (doE) {
        int k = t - 128;
        float s = 0.f, s2 = 0.f;
        for (int b = 0; b < SB; b++) {
            s += partialE[(size_t)b * 64 + k];
            s2 += partialE[(size_t)b * 64 + 32 + k];
        }
        float mu = s * (1.f / NE);
        float var = s2 * (1.f / NE) - mu * mu;
        float sc = rsqrtf(var + EPSV) * gE[k];
        scsh[256 + k] = sc;
        scsh[288 + k] = bE[k] - mu * sc;
    }
}

// ---------- out = lrelu(BN(h)) @ Wfc + bfc ----------
__global__ void k_out(const float* __restrict__ h, const float* __restrict__ scsh,
                      const float* __restrict__ Wfc, const float* __restrict__ bfc,
                      float* __restrict__ out) {
    int n = blockIdx.x * blockDim.x + threadIdx.x;
    if (n >= NN) return;
    const float* hr = h + (size_t)n * D;
    float s = bfc[0];
    for (int d = 0; d < D; d++) {
        float v = lrelu(hr[d] * scsh[d] + scsh[128 + d]);
        s += v * Wfc[d];
    }
    out[n] = s;
}

extern "C" void kernel_launch(void* const* d_in, const int* in_sizes, int n_in,
                              void* d_out, int out_size, void* d_ws, size_t ws_size,
                              hipStream_t stream) {
    const int* seq = (const int*)d_in[0];
    const int* sec = (const int*)d_in[1];
    const float* edge_p = (const float*)d_in[2];
    const int* src = (const int*)d_in[3];
    const int* dst = (const int*)d_in[4];
    const float* Wseq = (const float*)d_in[5];
    const float* Wsec = (const float*)d_in[6];
    const float* W0_node = (const float*)d_in[7];
    const float* b0_node = (const float*)d_in[8];
    const float* W0_ni = (const float*)d_in[9];
    const float* W0_fij = (const float*)d_in[10];
    const float* W0_nj = (const float*)d_in[11];
    const float* attn0 = (const float*)d_in[12];
    const float* ebias0 = (const float*)d_in[13];
    const float* Wn = (const float*)d_in[14];
    const float* bn = (const float*)d_in[15];
    const float* Wni = (const float*)d_in[16];
    const float* Wfij = (const float*)d_in[17];
    const float* Wnj = (const float*)d_in[18];
    const float* attnB = (const float*)d_in[19];
    const float* ebiasB = (const float*)d_in[20];
    const float* gn = (const float*)d_in[21];
    const float* betan = (const float*)d_in[22];
    const float* ge = (const float*)d_in[23];
    const float* betae = (const float*)d_in[24];
    const float* Wfc = (const float*)d_in[25];
    const float* bfc = (const float*)d_in[26];

    char* p = (char*)d_ws;
    auto alloc = [&](size_t bytes) -> char* {
        char* r = p;
        p += (bytes + 255) & ~(size_t)255;
        return r;
    };
    float* hA = (float*)alloc((size_t)NN * D * 4);
    float* hB = (float*)alloc((size_t)NN * D * 4);
    unsigned short* hp = (unsigned short*)alloc((size_t)NN * D * 2);      // bf16
    unsigned short* ebuf = (unsigned short*)alloc((size_t)NE * HE * 2);   // bf16, in-place
    float* logits = (float*)alloc((size_t)NE * HEADS * 4);                // [H][NE] planes
    float* ni = (float*)alloc((size_t)NN * HE * 4);
    float* nj = (float*)alloc((size_t)NN * HE * 4);
    int* esort = (int*)alloc((size_t)NE * 4);
    int* src_s = (int*)alloc((size_t)NE * 4);
    int* dst_s = (int*)alloc((size_t)NE * 4);
    float* ep_s = (float*)alloc((size_t)NE * 4);
    int* cnt = (int*)alloc((size_t)NN * 4);
    int* cursor = (int*)alloc((size_t)NN * 4);
    int* indptr = (int*)alloc((size_t)(NN + 1) * 4);
    int* bsum = (int*)alloc(256 * 4);
    int* bscan = (int*)alloc(256 * 4);
    float* partialH = (float*)alloc((size_t)SB * 256 * 4);
    float* partialE = (float*)alloc((size_t)SB * 64 * 4);
    float* scsh0 = (float*)alloc(320 * 4);
    float* scsh1 = (float*)alloc(320 * 4);

    const int EB = (NE + 255) / 256;   // 3125
    const int NB64 = (NN + 63) / 64;   // 782

    // CSR build + deterministic segment order + permuted edge arrays
    hipMemsetAsync(cnt, 0, (size_t)NN * 4, stream);
    hipMemsetAsync(cursor, 0, (size_t)NN * 4, stream);
    k_init_h<<<NN, 128, 0, stream>>>(seq, sec, Wseq, Wsec, hB);
    k_count<<<EB, 256, 0, stream>>>(dst, cnt);
    k_bsum<<<256, 256, 0, stream>>>(cnt, bsum);
    k_bscan<<<1, 256, 0, stream>>>(bsum, bscan, indptr);
    k_bwrite<<<256, 256, 0, stream>>>(cnt, bscan, indptr);
    k_scatter<<<EB, 256, 0, stream>>>(dst, indptr, cursor, esort);
    k_sortseg<<<(NN + 255) / 256, 256, 0, stream>>>(indptr, esort);
    k_permute<<<EB, 256, 0, stream>>>(esort, src, dst, edge_p, src_s, dst_s, ep_s);

    // ---- layer 0 (heads = 1), no BN ----
    k_node<0><<<NB64, 256, 0, stream>>>(hB, scsh0, W0_node, b0_node, W0_ni, W0_nj, hp, ni, nj);
    k_edge0<<<EB, 256, 0, stream>>>(ep_s, src_s, dst_s, ni, nj, W0_fij, attn0, ebias0, ebuf,
                                    logits);
    k_softmax<1><<<(NN + 255) / 256, 256, 0, stream>>>(indptr, logits);
    k_aggregate<1><<<(NN + 3) / 4, 256, 0, stream>>>(indptr, src_s, logits, hp, hA);

    // ---- deep layers (input hA for l=0; ping-pong) ----
    for (int l = 0; l < DEPTH; l++) {
        const float* Wn_l = Wn + (size_t)l * D * D;
        const float* bn_l = bn + (size_t)l * D;
        const float* Wni_l = Wni + (size_t)l * D * HE;
        const float* Wfij_l = Wfij + (size_t)l * HE * HE;
        const float* Wnj_l = Wnj + (size_t)l * D * HE;
        const float* attn_l = attnB + (size_t)l * HE;
        const float* eb_l = ebiasB + (size_t)l * HE;
        float* scshPrev = (l & 1) ? scsh0 : scsh1;
        float* scshCur = (l & 1) ? scsh1 : scsh0;
        float* hIn = (l & 1) ? hB : hA;
        float* hOut = (l & 1) ? hA : hB;

        if (l == 0)
            k_node<0><<<NB64, 256, 0, stream>>>(hIn, scshPrev, Wn_l, bn_l, Wni_l, Wnj_l, hp,
                                                ni, nj);
        else
            k_node<1><<<NB64, 256, 0, stream>>>(hIn, scshPrev, Wn_l, bn_l, Wni_l, Wnj_l, hp,
                                                ni, nj);

        if (l == 0)
            k_edgeB<1, 0><<<EB, 256, 0, stream>>>(ebuf, src_s, dst_s, ni, nj, Wfij_l, attn_l,
                                                  eb_l, scshPrev, ebuf, logits);
        else if (l == DEPTH - 1)
            k_edgeB<0, 1><<<EB, 256, 0, stream>>>(ebuf, src_s, dst_s, ni, nj, Wfij_l, attn_l,
                                                  eb_l, scshPrev, ebuf, logits);
        else
            k_edgeB<0, 0><<<EB, 256, 0, stream>>>(ebuf, src_s, dst_s, ni, nj, Wfij_l, attn_l,
                                                  eb_l, scshPrev, ebuf, logits);
        k_softmax<HEADS><<<(NN * HEADS + 255) / 256, 256, 0, stream>>>(indptr, logits);
        k_aggregate<HEADS><<<(NN + 3) / 4, 256, 0, stream>>>(indptr, src_s, logits, hp, hOut);

        k_bnstatsH<<<SB, 256, 0, stream>>>(hOut, partialH);
        if (l < DEPTH - 1) k_bnstatsE<<<SB, 256, 0, stream>>>(ebuf, partialE);
        k_bnprep<<<1, 160, 0, stream>>>(partialH, gn + (size_t)l * D, betan + (size_t)l * D,
                                        partialE, ge + (size_t)l * HE, betae + (size_t)l * HE,
                                        scshCur, l < DEPTH - 1 ? 1 : 0);
    }

    // final h is in hA (l=7 wrote hOut=hA); BN of layer 7 is in scsh1
    k_out<<<(NN + 255) / 256, 256, 0, stream>>>(hA, scsh1, Wfc, bfc, (float*)d_out);
}

// Round 12
// 2787.524 us; speedup vs baseline: 1.1606x; 1.1071x over previous
//
#include <hip/hip_runtime.h>

#define NN 50000
#define NE 800000
#define D 128
#define HE 32
#define HEADS 4
#define DEPTH 8
#define EPSV 1e-5f
#define SLOPE 0.01f
#define CHUNK 196  // 196*256 >= 50000
#define SBH 512    // H-stat blocks (fixed, deterministic reduce)
#define SBE 1024   // E-stat blocks

__device__ __forceinline__ float lrelu(float x) { return x > 0.f ? x : SLOPE * x; }

__device__ __forceinline__ float bf2f(unsigned short u) {
    union { float f; unsigned i; } c;
    c.i = ((unsigned)u) << 16;
    return c.f;
}
__device__ __forceinline__ unsigned short f2bf(float f) {
    union { float f; unsigned i; } c;
    c.f = f;
    unsigned r = c.i + 0x7FFFu + ((c.i >> 16) & 1u);  // RNE
    return (unsigned short)(r >> 16);
}
__device__ __forceinline__ unsigned pack2(float a, float b) {
    return (unsigned)f2bf(a) | ((unsigned)f2bf(b) << 16);
}
__device__ __forceinline__ void unpk2(unsigned u, float& a, float& b) {
    union { float f; unsigned i; } c;
    c.i = u << 16; a = c.f;
    c.i = u & 0xFFFF0000u; b = c.f;
}

// ---------- h init ----------
__global__ void k_init_h(const int* __restrict__ seq, const int* __restrict__ sec,
                         const float* __restrict__ Wseq, const float* __restrict__ Wsec,
                         float* __restrict__ h) {
    int n = blockIdx.x;
    int d = threadIdx.x;  // 128
    float v = (d < 96) ? Wseq[seq[n] * 96 + d] : Wsec[sec[n] * 32 + (d - 96)];
    h[(size_t)n * D + d] = v;
}

// ---------- CSR build ----------
__global__ void k_count(const int* __restrict__ dst, int* __restrict__ cnt) {
    int e = blockIdx.x * blockDim.x + threadIdx.x;
    if (e < NE) atomicAdd(&cnt[dst[e]], 1);
}

__global__ void k_bsum(const int* __restrict__ cnt, int* __restrict__ bsum) {
    __shared__ int sh[256];
    int b = blockIdx.x, tid = threadIdx.x;
    int idx = b * CHUNK + tid;
    int v = (tid < CHUNK && idx < NN) ? cnt[idx] : 0;
    sh[tid] = v;
    __syncthreads();
    for (int st = 128; st >= 1; st >>= 1) {
        if (tid < st) sh[tid] += sh[tid + st];
        __syncthreads();
    }
    if (tid == 0) bsum[b] = sh[0];
}

__global__ void k_bscan(const int* __restrict__ bsum, int* __restrict__ bscan,
                        int* __restrict__ indptr) {
    __shared__ int sh[256];
    int tid = threadIdx.x;
    int v = bsum[tid];
    sh[tid] = v;
    __syncthreads();
    for (int st = 1; st < 256; st <<= 1) {
        int t = (tid >= st) ? sh[tid - st] : 0;
        __syncthreads();
        sh[tid] += t;
        __syncthreads();
    }
    bscan[tid] = sh[tid] - v;  // exclusive
    if (tid == 255) indptr[NN] = sh[255];
}

__global__ void k_bwrite(const int* __restrict__ cnt, const int* __restrict__ bscan,
                         int* __restrict__ indptr) {
    __shared__ int sh[256];
    int b = blockIdx.x, tid = threadIdx.x;
    int idx = b * CHUNK + tid;
    int v = (tid < CHUNK && idx < NN) ? cnt[idx] : 0;
    sh[tid] = v;
    __syncthreads();
    for (int st = 1; st < 256; st <<= 1) {
        int t = (tid >= st) ? sh[tid - st] : 0;
        __syncthreads();
        sh[tid] += t;
        __syncthreads();
    }
    if (tid < CHUNK && idx < NN) indptr[idx] = bscan[b] + sh[tid] - v;
}

__global__ void k_scatter(const int* __restrict__ dst, const int* __restrict__ indptr,
                          int* __restrict__ cursor, int* __restrict__ esort) {
    int e = blockIdx.x * blockDim.x + threadIdx.x;
    if (e >= NE) return;
    int dn = dst[e];
    int pos = atomicAdd(&cursor[dn], 1);
    esort[indptr[dn] + pos] = e;
}

// ---------- deterministic segment order: sort each segment by edge id ----------
__global__ void k_sortseg(const int* __restrict__ indptr, int* __restrict__ esort) {
    int n = blockIdx.x * blockDim.x + threadIdx.x;
    if (n >= NN) return;
    int b = indptr[n], e = indptr[n + 1];
    for (int i = b + 1; i < e; i++) {
        int v = esort[i];
        int j = i - 1;
        while (j >= b && esort[j] > v) {
            esort[j + 1] = esort[j];
            j--;
        }
        esort[j + 1] = v;
    }
}

__global__ void k_permute(const int* __restrict__ esort, const int* __restrict__ src,
                          const int* __restrict__ dst, const float* __restrict__ edge_p,
                          int* __restrict__ src_s, int* __restrict__ dst_s,
                          float* __restrict__ ep_s) {
    int i = blockIdx.x * blockDim.x + threadIdx.x;
    if (i >= NE) return;
    int e = esort[i];
    src_s[i] = src[e];
    dst_s[i] = dst[e];
    ep_s[i] = edge_p[e];
}

// ---------- fused node kernel, W staged in LDS (double-buffered 8-row stages) ----------
template <int APPLY_BN>
__global__ __launch_bounds__(256) void k_node(
    const float* __restrict__ hin, const float* __restrict__ scsh,
    const float* __restrict__ Wn_, const float* __restrict__ bn_,
    const float* __restrict__ Wni_, const float* __restrict__ Wnj_,
    unsigned short* __restrict__ hp, float* __restrict__ ni, float* __restrict__ nj) {
    __shared__ float hs[64][132];
    __shared__ float wb[2][8][192];
    int tid = threadIdx.x;
    int n0 = blockIdx.x * 64;

    float4 wreg[2];
    int wf0 = tid, wf1 = tid + 256;
    auto wload = [&](int s) {
#pragma unroll
        for (int u = 0; u < 2; u++) {
            int f = (u == 0) ? wf0 : wf1;
            if (f < 384) {
                int rr = f / 48, c = (f % 48) * 4;
                int dd = s * 8 + rr;
                const float* sp;
                if (c < 128) sp = Wn_ + (size_t)dd * 128 + c;
                else if (c < 160) sp = Wni_ + (size_t)dd * 32 + (c - 128);
                else sp = Wnj_ + (size_t)dd * 32 + (c - 160);
                wreg[u] = *(const float4*)sp;
            }
        }
    };
    auto wstore = [&](int buf) {
#pragma unroll
        for (int u = 0; u < 2; u++) {
            int f = (u == 0) ? wf0 : wf1;
            if (f < 384) {
                int rr = f / 48, c = (f % 48) * 4;
                *(float4*)&wb[buf][rr][c] = wreg[u];
            }
        }
    };

    wload(0);
#pragma unroll
    for (int k = 0; k < 8; k++) {
        int f = tid + k * 256;
        int r = f >> 5, c4 = f & 31;
        int row = n0 + r;
        if (row >= NN) row = NN - 1;
        float4 v = *(const float4*)(hin + (size_t)row * D + c4 * 4);
        if (APPLY_BN) {
            float4 sc = *(const float4*)(scsh + c4 * 4);
            float4 sh = *(const float4*)(scsh + 128 + c4 * 4);
            v.x = lrelu(v.x * sc.x + sh.x);
            v.y = lrelu(v.y * sc.y + sh.y);
            v.z = lrelu(v.z * sc.z + sh.z);
            v.w = lrelu(v.w * sc.w + sh.w);
        }
        *(float4*)(&hs[r][c4 * 4]) = v;
    }
    wstore(0);
    __syncthreads();

    int rg = tid >> 4;  // 0..15
    int cg = tid & 15;  // 0..15
    int pcol = 128 + (cg & 7) * 4 + ((cg < 8) ? 0 : 32);
    float4 bA = *(const float4*)(bn_ + cg * 4);
    float4 bB = *(const float4*)(bn_ + 64 + cg * 4);
    float4 accA[4], accB[4], accC[4];
#pragma unroll
    for (int r = 0; r < 4; r++) {
        accA[r] = bA;
        accB[r] = bB;
        accC[r] = make_float4(0.f, 0.f, 0.f, 0.f);
    }

#define FMA4(acc_, hv_, w_)                                     \
    (acc_).x += (hv_) * (w_).x; (acc_).y += (hv_) * (w_).y;     \
    (acc_).z += (hv_) * (w_).z; (acc_).w += (hv_) * (w_).w;

    for (int s = 0; s < 16; s++) {
        int cur = s & 1;
        if (s < 15) wload(s + 1);
#pragma unroll
        for (int dd = 0; dd < 8; dd++) {
            int d = s * 8 + dd;
            float h0 = hs[rg * 4 + 0][d];
            float h1 = hs[rg * 4 + 1][d];
            float h2 = hs[rg * 4 + 2][d];
            float h3 = hs[rg * 4 + 3][d];
            float4 wv0 = *(const float4*)&wb[cur][dd][cg * 4];
            float4 wv1 = *(const float4*)&wb[cur][dd][64 + cg * 4];
            float4 wv2 = *(const float4*)&wb[cur][dd][pcol];
            FMA4(accA[0], h0, wv0) FMA4(accA[1], h1, wv0)
            FMA4(accA[2], h2, wv0) FMA4(accA[3], h3, wv0)
            FMA4(accB[0], h0, wv1) FMA4(accB[1], h1, wv1)
            FMA4(accB[2], h2, wv1) FMA4(accB[3], h3, wv1)
            FMA4(accC[0], h0, wv2) FMA4(accC[1], h1, wv2)
            FMA4(accC[2], h2, wv2) FMA4(accC[3], h3, wv2)
        }
        __syncthreads();
        if (s < 15) {
            wstore((s + 1) & 1);
            __syncthreads();
        }
    }

    float* projOut = (cg < 8) ? ni : nj;
    int pc = (cg & 7) * 4;
#pragma unroll
    for (int r = 0; r < 4; r++) {
        int row = n0 + rg * 4 + r;
        if (row < NN) {
            ushort4 pa = make_ushort4(f2bf(accA[r].x), f2bf(accA[r].y), f2bf(accA[r].z),
                                      f2bf(accA[r].w));
            ushort4 pb = make_ushort4(f2bf(accB[r].x), f2bf(accB[r].y), f2bf(accB[r].z),
                                      f2bf(accB[r].w));
            *(ushort4*)(hp + (size_t)row * D + cg * 4) = pa;
            *(ushort4*)(hp + (size_t)row * D + 64 + cg * 4) = pb;
            *(float4*)(projOut + (size_t)row * HE + pc) = accC[r];
        }
    }
}

// ---------- layer-0 edge kernel (heads=1, e = scalar edge_p) ----------
__global__ __launch_bounds__(256) void k_edge0(
    const float* __restrict__ ep_s, const int* __restrict__ src_s,
    const int* __restrict__ dst_s, const float* __restrict__ ni,
    const float* __restrict__ nj, const float* __restrict__ Wfij,
    const float* __restrict__ attn, const float* __restrict__ ebias,
    unsigned short* __restrict__ fout, float* __restrict__ logits) {
    __shared__ float sw[HE], sa[HE], se[HE];
    int tid = threadIdx.x;
    if (tid < HE) {
        sw[tid] = Wfij[tid];
        sa[tid] = attn[tid];
        se[tid] = ebias[tid];
    }
    __syncthreads();
    int i = blockIdx.x * blockDim.x + tid;
    if (i >= NE) return;
    int sn = src_s[i], dn = dst_s[i];
    float p = ep_s[i];
    const float4* niv = (const float4*)(ni + (size_t)sn * HE);
    const float4* njv = (const float4*)(nj + (size_t)dn * HE);
    float acc[HE];
#pragma unroll
    for (int j = 0; j < 8; j++) {
        float4 a = niv[j];
        float4 b = njv[j];
        acc[4 * j + 0] = se[4 * j + 0] + p * sw[4 * j + 0] + a.x + b.x;
        acc[4 * j + 1] = se[4 * j + 1] + p * sw[4 * j + 1] + a.y + b.y;
        acc[4 * j + 2] = se[4 * j + 2] + p * sw[4 * j + 2] + a.z + b.z;
        acc[4 * j + 3] = se[4 * j + 3] + p * sw[4 * j + 3] + a.w + b.w;
    }
    float lg = 0.f;
#pragma unroll
    for (int k = 0; k < HE; k++) {
        acc[k] = lrelu(acc[k]);
        lg += acc[k] * sa[k];
    }
    uint4* fo = (uint4*)(fout + (size_t)i * HE);
#pragma unroll
    for (int j = 0; j < 4; j++) {
        uint4 v;
        v.x = pack2(acc[8 * j + 0], acc[8 * j + 1]);
        v.y = pack2(acc[8 * j + 2], acc[8 * j + 3]);
        v.z = pack2(acc[8 * j + 4], acc[8 * j + 5]);
        v.w = pack2(acc[8 * j + 6], acc[8 * j + 7]);
        fo[j] = v;
    }
    logits[i] = lg;
}

// ---------- deep edge kernel (heads=4); 1 edge/thread, plane-major logits ----------
template <int FIRST, int LAST>
__global__ __launch_bounds__(256) void k_edgeB(
    const unsigned short* __restrict__ e_in, const int* __restrict__ src_s,
    const int* __restrict__ dst_s, const float* __restrict__ ni,
    const float* __restrict__ nj, const float* __restrict__ Wfij,
    const float* __restrict__ attn, const float* __restrict__ ebias,
    const float* __restrict__ scsh,  // [256..287]=scaleE, [288..319]=shiftE (prev layer)
    unsigned short* __restrict__ fout, float* __restrict__ logits) {
    int i = blockIdx.x * blockDim.x + threadIdx.x;
    if (i >= NE) return;
    int sn = src_s[i], dn = dst_s[i];
    const float4* niv = (const float4*)(ni + (size_t)sn * HE);
    const float4* njv = (const float4*)(nj + (size_t)dn * HE);
    float acc[HE];
#pragma unroll
    for (int j = 0; j < 8; j++) {
        float4 a = niv[j];
        float4 b = njv[j];
        acc[4 * j + 0] = ebias[4 * j + 0] + a.x + b.x;
        acc[4 * j + 1] = ebias[4 * j + 1] + a.y + b.y;
        acc[4 * j + 2] = ebias[4 * j + 2] + a.z + b.z;
        acc[4 * j + 3] = ebias[4 * j + 3] + a.w + b.w;
    }
    const uint4* ein4 = (const uint4*)(e_in + (size_t)i * HE);
#pragma unroll
    for (int j = 0; j < 4; j++) {
        uint4 ev = ein4[j];
        float ec[8];
        unpk2(ev.x, ec[0], ec[1]);
        unpk2(ev.y, ec[2], ec[3]);
        unpk2(ev.z, ec[4], ec[5]);
        unpk2(ev.w, ec[6], ec[7]);
#pragma unroll
        for (int c = 0; c < 8; c++) {
            int de = 8 * j + c;
            float x = ec[c];
            if (!FIRST) x = lrelu(x * scsh[256 + de] + scsh[288 + de]);
            const float* wr = Wfij + (size_t)de * HE;
#pragma unroll
            for (int k = 0; k < HE; k++) acc[k] += x * wr[k];
        }
    }
#pragma unroll
    for (int k = 0; k < HE; k++) acc[k] = lrelu(acc[k]);
    if (!LAST) {
        uint4* fo = (uint4*)(fout + (size_t)i * HE);
#pragma unroll
        for (int j = 0; j < 4; j++) {
            uint4 v;
            v.x = pack2(acc[8 * j + 0], acc[8 * j + 1]);
            v.y = pack2(acc[8 * j + 2], acc[8 * j + 3]);
            v.z = pack2(acc[8 * j + 4], acc[8 * j + 5]);
            v.w = pack2(acc[8 * j + 6], acc[8 * j + 7]);
            fo[j] = v;
        }
    }
#pragma unroll
    for (int hh = 0; hh < HEADS; hh++) {
        float s = 0.f;
#pragma unroll
        for (int j = 0; j < 8; j++) s += acc[hh * 8 + j] * attn[hh * 8 + j];
        logits[(size_t)hh * NE + i] = s;
    }
}

// ---------- segment softmax, plane-major logits [H][NE], in-place ----------
template <int H>
__global__ void k_softmax(const int* __restrict__ indptr, float* __restrict__ logits) {
    long t = (long)blockIdx.x * blockDim.x + threadIdx.x;
    if (t >= (long)NN * H) return;
    int n = (int)(t % NN);
    int hh = (int)(t / NN);
    float* lp = logits + (size_t)hh * NE;
    int b = indptr[n], e = indptr[n + 1];
    if (b == e) return;
    float m = -1e30f;
    for (int i = b; i < e; i++) m = fmaxf(m, lp[i]);
    float s = 0.f;
    for (int i = b; i < e; i++) {
        float z = __expf(lp[i] - m);
        lp[i] = z;
        s += z;
    }
    float inv = 1.f / s;
    for (int i = b; i < e; i++) lp[i] *= inv;
}

// ---------- aggregate: wave per node, 2 cols per lane, plane-major a ----------
template <int H>
__global__ __launch_bounds__(256) void k_aggregate(const int* __restrict__ indptr,
                                                   const int* __restrict__ src_s,
                                                   const float* __restrict__ a,
                                                   const unsigned short* __restrict__ hp,
                                                   float* __restrict__ hacc) {
    int n = blockIdx.x * 4 + (threadIdx.x >> 6);
    if (n >= NN) return;
    int lane = threadIdx.x & 63;
    int c2 = lane * 2;  // cols c2, c2+1
    int b = indptr[n], e = indptr[n + 1];
    int hh = (H == 1) ? 0 : (c2 >> 5);
    const float* ap = a + (size_t)hh * NE;
    float acc0 = 0.f, acc1 = 0.f;
#pragma unroll 4
    for (int i = b; i < e; i++) {
        float w = ap[i];
        unsigned u = *(const unsigned*)(hp + (size_t)src_s[i] * D + c2);
        float x0, x1;
        unpk2(u, x0, x1);
        acc0 += w * x0;
        acc1 += w * x1;
    }
    *(float2*)(hacc + (size_t)n * D + c2) = make_float2(acc0, acc1);
}

// ---------- BN stats H: float4 loads, 512 blocks, deterministic partials ----------
// partialH layout: [SBH][256] = [block][0..127 sum | 128..255 sumsq]
__global__ __launch_bounds__(256) void k_bnstatsH(const float* __restrict__ x,
                                                  float* __restrict__ partialH) {
    __shared__ float4 shs[256], shq[256];
    int tid = threadIdx.x;
    int c4 = (tid & 31) * 4;  // col group (4 cols)
    int r0 = tid >> 5;        // 0..7
    float4 s = make_float4(0.f, 0.f, 0.f, 0.f);
    float4 q = make_float4(0.f, 0.f, 0.f, 0.f);
    for (long r = (long)blockIdx.x * 8 + r0; r < NN; r += (long)SBH * 8) {
        float4 v = *(const float4*)(x + r * D + c4);
        s.x += v.x; s.y += v.y; s.z += v.z; s.w += v.w;
        q.x += v.x * v.x; q.y += v.y * v.y; q.z += v.z * v.z; q.w += v.w * v.w;
    }
    shs[tid] = s;
    shq[tid] = q;
    __syncthreads();
    for (int st = 128; st >= 32; st >>= 1) {
        if (tid < st) {
            float4 a = shs[tid], b = shs[tid + st];
            a.x += b.x; a.y += b.y; a.z += b.z; a.w += b.w;
            shs[tid] = a;
            float4 c = shq[tid], d = shq[tid + st];
            c.x += d.x; c.y += d.y; c.z += d.z; c.w += d.w;
            shq[tid] = c;
        }
        __syncthreads();
    }
    if (tid < 32) {
        *(float4*)&partialH[(size_t)blockIdx.x * 256 + 4 * tid] = shs[tid];
        *(float4*)&partialH[(size_t)blockIdx.x * 256 + 128 + 4 * tid] = shq[tid];
    }
}

// ---------- BN stats E: u32 loads, 1024 blocks, deterministic partials ----------
// partialE layout: [SBE][64] = [block][0..31 sum | 32..63 sumsq]
__global__ __launch_bounds__(256) void k_bnstatsE(const unsigned short* __restrict__ x,
                                                  float* __restrict__ partialE) {
    __shared__ float shs0[256], shs1[256], shq0[256], shq1[256];
    int tid = threadIdx.x;
    int d = tid & 15;   // u32 col group: cols 2d, 2d+1
    int r0 = tid >> 4;  // 0..15
    float s0 = 0.f, s1 = 0.f, q0 = 0.f, q1 = 0.f;
    for (long r = (long)blockIdx.x * 16 + r0; r < NE; r += (long)SBE * 16) {
        unsigned u = *(const unsigned*)(x + r * HE + 2 * d);
        float a, b;
        unpk2(u, a, b);
        s0 += a; s1 += b;
        q0 += a * a; q1 += b * b;
    }
    shs0[tid] = s0; shs1[tid] = s1;
    shq0[tid] = q0; shq1[tid] = q1;
    __syncthreads();
    for (int st = 128; st >= 16; st >>= 1) {
        if (tid < st) {
            shs0[tid] += shs0[tid + st];
            shs1[tid] += shs1[tid + st];
            shq0[tid] += shq0[tid + st];
            shq1[tid] += shq1[tid + st];
        }
        __syncthreads();
    }
    if (tid < 16) {
        partialE[(size_t)blockIdx.x * 64 + 2 * tid] = shs0[tid];
        partialE[(size_t)blockIdx.x * 64 + 2 * tid + 1] = shs1[tid];
        partialE[(size_t)blockIdx.x * 64 + 32 + 2 * tid] = shq0[tid];
        partialE[(size_t)blockIdx.x * 64 + 32 + 2 * tid + 1] = shq1[tid];
    }
}

// ---------- BN scale/shift prep: fixed-order reduce of partials ----------
__global__ void k_bnprep(const float* __restrict__ partialH, const float* __restrict__ gH,
                         const float* __restrict__ bH, const float* __restrict__ partialE,
                         const float* __restrict__ gE, const float* __restrict__ bE,
                         float* __restrict__ scsh, int doE) {
    int t = threadIdx.x;  // 160
    if (t < 128) {
        float s = 0.f, s2 = 0.f;
#pragma unroll 4
        for (int b = 0; b < SBH; b++) {
            s += partialH[(size_t)b * 256 + t];
            s2 += partialH[(size_t)b * 256 + 128 + t];
        }
        float mu = s * (1.f / NN);
        float var = s2 * (1.f / NN) - mu * mu;
        float sc = rsqrtf(var + EPSV) * gH[t];
        scsh[t] = sc;
        scsh[128 + t] = bH[t] - mu * sc;
    } else if (doE) {
        int k = t - 128;
        float s = 0.f, s2 = 0.f;
#pragma unroll 4
        for (int b = 0; b < SBE; b++) {
            s += partialE[(size_t)b * 64 + k];
            s2 += partialE[(size_t)b * 64 + 32 + k];
        }
        float mu = s * (1.f / NE);
        float var = s2 * (1.f / NE) - mu * mu;
        float sc = rsqrtf(var + EPSV) * gE[k];
        scsh[256 + k] = sc;
        scsh[288 + k] = bE[k] - mu * sc;
    }
}

// ---------- out = lrelu(BN(h)) @ Wfc + bfc ----------
__global__ void k_out(const float* __restrict__ h, const float* __restrict__ scsh,
                      const float* __restrict__ Wfc, const float* __restrict__ bfc,
                      float* __restrict__ out) {
    int n = blockIdx.x * blockDim.x + threadIdx.x;
    if (n >= NN) return;
    const float* hr = h + (size_t)n * D;
    float s = bfc[0];
    for (int d = 0; d < D; d++) {
        float v = lrelu(hr[d] * scsh[d] + scsh[128 + d]);
        s += v * Wfc[d];
    }
    out[n] = s;
}

extern "C" void kernel_launch(void* const* d_in, const int* in_sizes, int n_in,
                              void* d_out, int out_size, void* d_ws, size_t ws_size,
                              hipStream_t stream) {
    const int* seq = (const int*)d_in[0];
    const int* sec = (const int*)d_in[1];
    const float* edge_p = (const float*)d_in[2];
    const int* src = (const int*)d_in[3];
    const int* dst = (const int*)d_in[4];
    const float* Wseq = (const float*)d_in[5];
    const float* Wsec = (const float*)d_in[6];
    const float* W0_node = (const float*)d_in[7];
    const float* b0_node = (const float*)d_in[8];
    const float* W0_ni = (const float*)d_in[9];
    const float* W0_fij = (const float*)d_in[10];
    const float* W0_nj = (const float*)d_in[11];
    const float* attn0 = (const float*)d_in[12];
    const float* ebias0 = (const float*)d_in[13];
    const float* Wn = (const float*)d_in[14];
    const float* bn = (const float*)d_in[15];
    const float* Wni = (const float*)d_in[16];
    const float* Wfij = (const float*)d_in[17];
    const float* Wnj = (const float*)d_in[18];
    const float* attnB = (const float*)d_in[19];
    const float* ebiasB = (const float*)d_in[20];
    const float* gn = (const float*)d_in[21];
    const float* betan = (const float*)d_in[22];
    const float* ge = (const float*)d_in[23];
    const float* betae = (const float*)d_in[24];
    const float* Wfc = (const float*)d_in[25];
    const float* bfc = (const float*)d_in[26];

    char* p = (char*)d_ws;
    auto alloc = [&](size_t bytes) -> char* {
        char* r = p;
        p += (bytes + 255) & ~(size_t)255;
        return r;
    };
    float* hA = (float*)alloc((size_t)NN * D * 4);
    float* hB = (float*)alloc((size_t)NN * D * 4);
    unsigned short* hp = (unsigned short*)alloc((size_t)NN * D * 2);      // bf16
    unsigned short* ebuf = (unsigned short*)alloc((size_t)NE * HE * 2);   // bf16, in-place
    float* logits = (float*)alloc((size_t)NE * HEADS * 4);                // [H][NE] planes
    float* ni = (float*)alloc((size_t)NN * HE * 4);
    float* nj = (float*)alloc((size_t)NN * HE * 4);
    int* esort = (int*)alloc((size_t)NE * 4);
    int* src_s = (int*)alloc((size_t)NE * 4);
    int* dst_s = (int*)alloc((size_t)NE * 4);
    float* ep_s = (float*)alloc((size_t)NE * 4);
    int* cnt = (int*)alloc((size_t)NN * 4);
    int* cursor = (int*)alloc((size_t)NN * 4);
    int* indptr = (int*)alloc((size_t)(NN + 1) * 4);
    int* bsum = (int*)alloc(256 * 4);
    int* bscan = (int*)alloc(256 * 4);
    float* partialH = (float*)alloc((size_t)SBH * 256 * 4);
    float* partialE = (float*)alloc((size_t)SBE * 64 * 4);
    float* scsh0 = (float*)alloc(320 * 4);
    float* scsh1 = (float*)alloc(320 * 4);

    const int EB = (NE + 255) / 256;   // 3125
    const int NB64 = (NN + 63) / 64;   // 782

    // CSR build + deterministic segment order + permuted edge arrays
    hipMemsetAsync(cnt, 0, (size_t)NN * 4, stream);
    hipMemsetAsync(cursor, 0, (size_t)NN * 4, stream);
    k_init_h<<<NN, 128, 0, stream>>>(seq, sec, Wseq, Wsec, hB);
    k_count<<<EB, 256, 0, stream>>>(dst, cnt);
    k_bsum<<<256, 256, 0, stream>>>(cnt, bsum);
    k_bscan<<<1, 256, 0, stream>>>(bsum, bscan, indptr);
    k_bwrite<<<256, 256, 0, stream>>>(cnt, bscan, indptr);
    k_scatter<<<EB, 256, 0, stream>>>(dst, indptr, cursor, esort);
    k_sortseg<<<(NN + 255) / 256, 256, 0, stream>>>(indptr, esort);
    k_permute<<<EB, 256, 0, stream>>>(esort, src, dst, edge_p, src_s, dst_s, ep_s);

    // ---- layer 0 (heads = 1), no BN ----
    k_node<0><<<NB64, 256, 0, stream>>>(hB, scsh0, W0_node, b0_node, W0_ni, W0_nj, hp, ni, nj);
    k_edge0<<<EB, 256, 0, stream>>>(ep_s, src_s, dst_s, ni, nj, W0_fij, attn0, ebias0, ebuf,
                                    logits);
    k_softmax<1><<<(NN + 255) / 256, 256, 0, stream>>>(indptr, logits);
    k_aggregate<1><<<(NN + 3) / 4, 256, 0, stream>>>(indptr, src_s, logits, hp, hA);

    // ---- deep layers (input hA for l=0; ping-pong) ----
    for (int l = 0; l < DEPTH; l++) {
        const float* Wn_l = Wn + (size_t)l * D * D;
        const float* bn_l = bn + (size_t)l * D;
        const float* Wni_l = Wni + (size_t)l * D * HE;
        const float* Wfij_l = Wfij + (size_t)l * HE * HE;
        const float* Wnj_l = Wnj + (size_t)l * D * HE;
        const float* attn_l = attnB + (size_t)l * HE;
        const float* eb_l = ebiasB + (size_t)l * HE;
        float* scshPrev = (l & 1) ? scsh0 : scsh1;
        float* scshCur = (l & 1) ? scsh1 : scsh0;
        float* hIn = (l & 1) ? hB : hA;
        float* hOut = (l & 1) ? hA : hB;

        if (l == 0)
            k_node<0><<<NB64, 256, 0, stream>>>(hIn, scshPrev, Wn_l, bn_l, Wni_l, Wnj_l, hp,
                                                ni, nj);
        else
            k_node<1><<<NB64, 256, 0, stream>>>(hIn, scshPrev, Wn_l, bn_l, Wni_l, Wnj_l, hp,
                                                ni, nj);

        if (l == 0)
            k_edgeB<1, 0><<<EB, 256, 0, stream>>>(ebuf, src_s, dst_s, ni, nj, Wfij_l, attn_l,
                                                  eb_l, scshPrev, ebuf, logits);
        else if (l == DEPTH - 1)
            k_edgeB<0, 1><<<EB, 256, 0, stream>>>(ebuf, src_s, dst_s, ni, nj, Wfij_l, attn_l,
                                                  eb_l, scshPrev, ebuf, logits);
        else
            k_edgeB<0, 0><<<EB, 256, 0, stream>>>(ebuf, src_s, dst_s, ni, nj, Wfij_l, attn_l,
                                                  eb_l, scshPrev, ebuf, logits);
        k_softmax<HEADS><<<(NN * HEADS + 255) / 256, 256, 0, stream>>>(indptr, logits);
        k_aggregate<HEADS><<<(NN + 3) / 4, 256, 0, stream>>>(indptr, src_s, logits, hp, hOut);

        k_bnstatsH<<<SBH, 256, 0, stream>>>(hOut, partialH);
        if (l < DEPTH - 1) k_bnstatsE<<<SBE, 256, 0, stream>>>(ebuf, partialE);
        k_bnprep<<<1, 160, 0, stream>>>(partialH, gn + (size_t)l * D, betan + (size_t)l * D,
                                        partialE, ge + (size_t)l * HE, betae + (size_t)l * HE,
                                        scshCur, l < DEPTH - 1 ? 1 : 0);
    }

    // final h is in hA (l=7 wrote hOut=hA); BN of layer 7 is in scsh1
    k_out<<<(NN + 255) / 256, 256, 0, stream>>>(hA, scsh1, Wfc, bfc, (float*)d_out);
}

// Round 13
// 2058.432 us; speedup vs baseline: 1.5716x; 1.3542x over previous
//
#include <hip/hip_runtime.h>

#define NN 50000
#define NE 800000
#define D 128
#define HE 32
#define HEADS 4
#define DEPTH 8
#define EPSV 1e-5f
#define SLOPE 0.01f
#define CHUNK 196  // 196*256 >= 50000
#define SBH 512    // H-stat blocks (fixed, deterministic reduce)
#define SBE 1024   // E-stat blocks

__device__ __forceinline__ float lrelu(float x) { return x > 0.f ? x : SLOPE * x; }

__device__ __forceinline__ float bf2f(unsigned short u) {
    union { float f; unsigned i; } c;
    c.i = ((unsigned)u) << 16;
    return c.f;
}
__device__ __forceinline__ unsigned short f2bf(float f) {
    union { float f; unsigned i; } c;
    c.f = f;
    unsigned r = c.i + 0x7FFFu + ((c.i >> 16) & 1u);  // RNE
    return (unsigned short)(r >> 16);
}
__device__ __forceinline__ unsigned pack2(float a, float b) {
    return (unsigned)f2bf(a) | ((unsigned)f2bf(b) << 16);
}
__device__ __forceinline__ void unpk2(unsigned u, float& a, float& b) {
    union { float f; unsigned i; } c;
    c.i = u << 16; a = c.f;
    c.i = u & 0xFFFF0000u; b = c.f;
}

// ---------- h init ----------
__global__ void k_init_h(const int* __restrict__ seq, const int* __restrict__ sec,
                         const float* __restrict__ Wseq, const float* __restrict__ Wsec,
                         float* __restrict__ h) {
    int n = blockIdx.x;
    int d = threadIdx.x;  // 128
    float v = (d < 96) ? Wseq[seq[n] * 96 + d] : Wsec[sec[n] * 32 + (d - 96)];
    h[(size_t)n * D + d] = v;
}

// ---------- CSR build ----------
__global__ void k_count(const int* __restrict__ dst, int* __restrict__ cnt) {
    int e = blockIdx.x * blockDim.x + threadIdx.x;
    if (e < NE) atomicAdd(&cnt[dst[e]], 1);
}

__global__ void k_bsum(const int* __restrict__ cnt, int* __restrict__ bsum) {
    __shared__ int sh[256];
    int b = blockIdx.x, tid = threadIdx.x;
    int idx = b * CHUNK + tid;
    int v = (tid < CHUNK && idx < NN) ? cnt[idx] : 0;
    sh[tid] = v;
    __syncthreads();
    for (int st = 128; st >= 1; st >>= 1) {
        if (tid < st) sh[tid] += sh[tid + st];
        __syncthreads();
    }
    if (tid == 0) bsum[b] = sh[0];
}

__global__ void k_bscan(const int* __restrict__ bsum, int* __restrict__ bscan,
                        int* __restrict__ indptr) {
    __shared__ int sh[256];
    int tid = threadIdx.x;
    int v = bsum[tid];
    sh[tid] = v;
    __syncthreads();
    for (int st = 1; st < 256; st <<= 1) {
        int t = (tid >= st) ? sh[tid - st] : 0;
        __syncthreads();
        sh[tid] += t;
        __syncthreads();
    }
    bscan[tid] = sh[tid] - v;  // exclusive
    if (tid == 255) indptr[NN] = sh[255];
}

__global__ void k_bwrite(const int* __restrict__ cnt, const int* __restrict__ bscan,
                         int* __restrict__ indptr) {
    __shared__ int sh[256];
    int b = blockIdx.x, tid = threadIdx.x;
    int idx = b * CHUNK + tid;
    int v = (tid < CHUNK && idx < NN) ? cnt[idx] : 0;
    sh[tid] = v;
    __syncthreads();
    for (int st = 1; st < 256; st <<= 1) {
        int t = (tid >= st) ? sh[tid - st] : 0;
        __syncthreads();
        sh[tid] += t;
        __syncthreads();
    }
    if (tid < CHUNK && idx < NN) indptr[idx] = bscan[b] + sh[tid] - v;
}

__global__ void k_scatter(const int* __restrict__ dst, const int* __restrict__ indptr,
                          int* __restrict__ cursor, int* __restrict__ esort) {
    int e = blockIdx.x * blockDim.x + threadIdx.x;
    if (e >= NE) return;
    int dn = dst[e];
    int pos = atomicAdd(&cursor[dn], 1);
    esort[indptr[dn] + pos] = e;
}

// ---------- deterministic segment order: sort each segment by edge id ----------
__global__ void k_sortseg(const int* __restrict__ indptr, int* __restrict__ esort) {
    int n = blockIdx.x * blockDim.x + threadIdx.x;
    if (n >= NN) return;
    int b = indptr[n], e = indptr[n + 1];
    for (int i = b + 1; i < e; i++) {
        int v = esort[i];
        int j = i - 1;
        while (j >= b && esort[j] > v) {
            esort[j + 1] = esort[j];
            j--;
        }
        esort[j + 1] = v;
    }
}

__global__ void k_permute(const int* __restrict__ esort, const int* __restrict__ src,
                          const int* __restrict__ dst, const float* __restrict__ edge_p,
                          int* __restrict__ src_s, int* __restrict__ dst_s,
                          float* __restrict__ ep_s) {
    int i = blockIdx.x * blockDim.x + threadIdx.x;
    if (i >= NE) return;
    int e = esort[i];
    src_s[i] = src[e];
    dst_s[i] = dst[e];
    ep_s[i] = edge_p[e];
}

// ---------- fused node kernel, W staged in LDS (double-buffered 8-row stages) ----------
template <int APPLY_BN>
__global__ __launch_bounds__(256) void k_node(
    const float* __restrict__ hin, const float* __restrict__ scsh,
    const float* __restrict__ Wn_, const float* __restrict__ bn_,
    const float* __restrict__ Wni_, const float* __restrict__ Wnj_,
    unsigned short* __restrict__ hp, float* __restrict__ ni, float* __restrict__ nj) {
    __shared__ float hs[64][132];
    __shared__ float wb[2][8][192];
    int tid = threadIdx.x;
    int n0 = blockIdx.x * 64;

    float4 wreg[2];
    int wf0 = tid, wf1 = tid + 256;
    auto wload = [&](int s) {
#pragma unroll
        for (int u = 0; u < 2; u++) {
            int f = (u == 0) ? wf0 : wf1;
            if (f < 384) {
                int rr = f / 48, c = (f % 48) * 4;
                int dd = s * 8 + rr;
                const float* sp;
                if (c < 128) sp = Wn_ + (size_t)dd * 128 + c;
                else if (c < 160) sp = Wni_ + (size_t)dd * 32 + (c - 128);
                else sp = Wnj_ + (size_t)dd * 32 + (c - 160);
                wreg[u] = *(const float4*)sp;
            }
        }
    };
    auto wstore = [&](int buf) {
#pragma unroll
        for (int u = 0; u < 2; u++) {
            int f = (u == 0) ? wf0 : wf1;
            if (f < 384) {
                int rr = f / 48, c = (f % 48) * 4;
                *(float4*)&wb[buf][rr][c] = wreg[u];
            }
        }
    };

    wload(0);
#pragma unroll
    for (int k = 0; k < 8; k++) {
        int f = tid + k * 256;
        int r = f >> 5, c4 = f & 31;
        int row = n0 + r;
        if (row >= NN) row = NN - 1;
        float4 v = *(const float4*)(hin + (size_t)row * D + c4 * 4);
        if (APPLY_BN) {
            float4 sc = *(const float4*)(scsh + c4 * 4);
            float4 sh = *(const float4*)(scsh + 128 + c4 * 4);
            v.x = lrelu(v.x * sc.x + sh.x);
            v.y = lrelu(v.y * sc.y + sh.y);
            v.z = lrelu(v.z * sc.z + sh.z);
            v.w = lrelu(v.w * sc.w + sh.w);
        }
        *(float4*)(&hs[r][c4 * 4]) = v;
    }
    wstore(0);
    __syncthreads();

    int rg = tid >> 4;  // 0..15
    int cg = tid & 15;  // 0..15
    int pcol = 128 + (cg & 7) * 4 + ((cg < 8) ? 0 : 32);
    float4 bA = *(const float4*)(bn_ + cg * 4);
    float4 bB = *(const float4*)(bn_ + 64 + cg * 4);
    float4 accA[4], accB[4], accC[4];
#pragma unroll
    for (int r = 0; r < 4; r++) {
        accA[r] = bA;
        accB[r] = bB;
        accC[r] = make_float4(0.f, 0.f, 0.f, 0.f);
    }

#define FMA4(acc_, hv_, w_)                                     \
    (acc_).x += (hv_) * (w_).x; (acc_).y += (hv_) * (w_).y;     \
    (acc_).z += (hv_) * (w_).z; (acc_).w += (hv_) * (w_).w;

    for (int s = 0; s < 16; s++) {
        int cur = s & 1;
        if (s < 15) wload(s + 1);
#pragma unroll
        for (int dd = 0; dd < 8; dd++) {
            int d = s * 8 + dd;
            float h0 = hs[rg * 4 + 0][d];
            float h1 = hs[rg * 4 + 1][d];
            float h2 = hs[rg * 4 + 2][d];
            float h3 = hs[rg * 4 + 3][d];
            float4 wv0 = *(const float4*)&wb[cur][dd][cg * 4];
            float4 wv1 = *(const float4*)&wb[cur][dd][64 + cg * 4];
            float4 wv2 = *(const float4*)&wb[cur][dd][pcol];
            FMA4(accA[0], h0, wv0) FMA4(accA[1], h1, wv0)
            FMA4(accA[2], h2, wv0) FMA4(accA[3], h3, wv0)
            FMA4(accB[0], h0, wv1) FMA4(accB[1], h1, wv1)
            FMA4(accB[2], h2, wv1) FMA4(accB[3], h3, wv1)
            FMA4(accC[0], h0, wv2) FMA4(accC[1], h1, wv2)
            FMA4(accC[2], h2, wv2) FMA4(accC[3], h3, wv2)
        }
        __syncthreads();
        if (s < 15) {
            wstore((s + 1) & 1);
            __syncthreads();
        }
    }

    float* projOut = (cg < 8) ? ni : nj;
    int pc = (cg & 7) * 4;
#pragma unroll
    for (int r = 0; r < 4; r++) {
        int row = n0 + rg * 4 + r;
        if (row < NN) {
            ushort4 pa = make_ushort4(f2bf(accA[r].x), f2bf(accA[r].y), f2bf(accA[r].z),
                                      f2bf(accA[r].w));
            ushort4 pb = make_ushort4(f2bf(accB[r].x), f2bf(accB[r].y), f2bf(accB[r].z),
                                      f2bf(accB[r].w));
            *(ushort4*)(hp + (size_t)row * D + cg * 4) = pa;
            *(ushort4*)(hp + (size_t)row * D + 64 + cg * 4) = pb;
            *(float4*)(projOut + (size_t)row * HE + pc) = accC[r];
        }
    }
}

// ---------- layer-0 edge kernel (heads=1, e = scalar edge_p) ----------
__global__ __launch_bounds__(256) void k_edge0(
    const float* __restrict__ ep_s, const int* __restrict__ src_s,
    const int* __restrict__ dst_s, const float* __restrict__ ni,
    const float* __restrict__ nj, const float* __restrict__ Wfij,
    const float* __restrict__ attn, const float* __restrict__ ebias,
    unsigned short* __restrict__ fout, float* __restrict__ logits) {
    __shared__ float sw[HE], sa[HE], se[HE];
    int tid = threadIdx.x;
    if (tid < HE) {
        sw[tid] = Wfij[tid];
        sa[tid] = attn[tid];
        se[tid] = ebias[tid];
    }
    __syncthreads();
    int i = blockIdx.x * blockDim.x + tid;
    if (i >= NE) return;
    int sn = src_s[i], dn = dst_s[i];
    float p = ep_s[i];
    const float4* niv = (const float4*)(ni + (size_t)sn * HE);
    const float4* njv = (const float4*)(nj + (size_t)dn * HE);
    float acc[HE];
#pragma unroll
    for (int j = 0; j < 8; j++) {
        float4 a = niv[j];
        float4 b = njv[j];
        acc[4 * j + 0] = se[4 * j + 0] + p * sw[4 * j + 0] + a.x + b.x;
        acc[4 * j + 1] = se[4 * j + 1] + p * sw[4 * j + 1] + a.y + b.y;
        acc[4 * j + 2] = se[4 * j + 2] + p * sw[4 * j + 2] + a.z + b.z;
        acc[4 * j + 3] = se[4 * j + 3] + p * sw[4 * j + 3] + a.w + b.w;
    }
    float lg = 0.f;
#pragma unroll
    for (int k = 0; k < HE; k++) {
        acc[k] = lrelu(acc[k]);
        lg += acc[k] * sa[k];
    }
    uint4* fo = (uint4*)(fout + (size_t)i * HE);
#pragma unroll
    for (int j = 0; j < 4; j++) {
        uint4 v;
        v.x = pack2(acc[8 * j + 0], acc[8 * j + 1]);
        v.y = pack2(acc[8 * j + 2], acc[8 * j + 3]);
        v.z = pack2(acc[8 * j + 4], acc[8 * j + 5]);
        v.w = pack2(acc[8 * j + 6], acc[8 * j + 7]);
        fo[j] = v;
    }
    logits[i] = lg;
}

// ---------- deep edge kernel (heads=4); 1 edge/thread, plane-major logits ----------
template <int FIRST, int LAST>
__global__ __launch_bounds__(256) void k_edgeB(
    const unsigned short* __restrict__ e_in, const int* __restrict__ src_s,
    const int* __restrict__ dst_s, const float* __restrict__ ni,
    const float* __restrict__ nj, const float* __restrict__ Wfij,
    const float* __restrict__ attn, const float* __restrict__ ebias,
    const float* __restrict__ scsh,  // [256..287]=scaleE, [288..319]=shiftE (prev layer)
    unsigned short* __restrict__ fout, float* __restrict__ logits) {
    int i = blockIdx.x * blockDim.x + threadIdx.x;
    if (i >= NE) return;
    int sn = src_s[i], dn = dst_s[i];
    const float4* niv = (const float4*)(ni + (size_t)sn * HE);
    const float4* njv = (const float4*)(nj + (size_t)dn * HE);
    float acc[HE];
#pragma unroll
    for (int j = 0; j < 8; j++) {
        float4 a = niv[j];
        float4 b = njv[j];
        acc[4 * j + 0] = ebias[4 * j + 0] + a.x + b.x;
        acc[4 * j + 1] = ebias[4 * j + 1] + a.y + b.y;
        acc[4 * j + 2] = ebias[4 * j + 2] + a.z + b.z;
        acc[4 * j + 3] = ebias[4 * j + 3] + a.w + b.w;
    }
    const uint4* ein4 = (const uint4*)(e_in + (size_t)i * HE);
#pragma unroll
    for (int j = 0; j < 4; j++) {
        uint4 ev = ein4[j];
        float ec[8];
        unpk2(ev.x, ec[0], ec[1]);
        unpk2(ev.y, ec[2], ec[3]);
        unpk2(ev.z, ec[4], ec[5]);
        unpk2(ev.w, ec[6], ec[7]);
#pragma unroll
        for (int c = 0; c < 8; c++) {
            int de = 8 * j + c;
            float x = ec[c];
            if (!FIRST) x = lrelu(x * scsh[256 + de] + scsh[288 + de]);
            const float* wr = Wfij + (size_t)de * HE;
#pragma unroll
            for (int k = 0; k < HE; k++) acc[k] += x * wr[k];
        }
    }
#pragma unroll
    for (int k = 0; k < HE; k++) acc[k] = lrelu(acc[k]);
    if (!LAST) {
        uint4* fo = (uint4*)(fout + (size_t)i * HE);
#pragma unroll
        for (int j = 0; j < 4; j++) {
            uint4 v;
            v.x = pack2(acc[8 * j + 0], acc[8 * j + 1]);
            v.y = pack2(acc[8 * j + 2], acc[8 * j + 3]);
            v.z = pack2(acc[8 * j + 4], acc[8 * j + 5]);
            v.w = pack2(acc[8 * j + 6], acc[8 * j + 7]);
            fo[j] = v;
        }
    }
#pragma unroll
    for (int hh = 0; hh < HEADS; hh++) {
        float s = 0.f;
#pragma unroll
        for (int j = 0; j < 8; j++) s += acc[hh * 8 + j] * attn[hh * 8 + j];
        logits[(size_t)hh * NE + i] = s;
    }
}

// ---------- softmax stats: per (node,head) max + 1/sum(exp); no logits rewrite ----------
template <int H>
__global__ void k_smstat(const int* __restrict__ indptr, const float* __restrict__ logits,
                         float2* __restrict__ minv) {
    long t = (long)blockIdx.x * blockDim.x + threadIdx.x;
    if (t >= (long)NN * H) return;
    int n = (int)(t % NN);
    int hh = (int)(t / NN);
    const float* lp = logits + (size_t)hh * NE;
    int b = indptr[n], e = indptr[n + 1];
    if (b == e) {
        minv[(size_t)hh * NN + n] = make_float2(0.f, 0.f);
        return;
    }
    float m = -1e30f;
    for (int i = b; i < e; i++) m = fmaxf(m, lp[i]);
    float s = 0.f;
    for (int i = b; i < e; i++) s += __expf(lp[i] - m);
    minv[(size_t)hh * NN + n] = make_float2(m, 1.f / s);
}

// ---------- aggregate: wave per node, 2 cols/lane; applies exp(l-m)*inv inline ----------
template <int H>
__global__ __launch_bounds__(256) void k_aggregate(const int* __restrict__ indptr,
                                                   const int* __restrict__ src_s,
                                                   const float* __restrict__ logits,
                                                   const float2* __restrict__ minv,
                                                   const unsigned short* __restrict__ hp,
                                                   float* __restrict__ hacc) {
    int n = blockIdx.x * 4 + (threadIdx.x >> 6);
    if (n >= NN) return;
    int lane = threadIdx.x & 63;
    int c2 = lane * 2;  // cols c2, c2+1
    int b = indptr[n], e = indptr[n + 1];
    int hh = (H == 1) ? 0 : (c2 >> 5);
    const float* lp = logits + (size_t)hh * NE;
    float2 mi = minv[(size_t)hh * NN + n];
    float acc0 = 0.f, acc1 = 0.f;
#pragma unroll 8
    for (int i = b; i < e; i++) {
        float w = __expf(lp[i] - mi.x) * mi.y;
        unsigned u = *(const unsigned*)(hp + (size_t)src_s[i] * D + c2);
        float x0, x1;
        unpk2(u, x0, x1);
        acc0 += w * x0;
        acc1 += w * x1;
    }
    *(float2*)(hacc + (size_t)n * D + c2) = make_float2(acc0, acc1);
}

// ---------- BN stats, merged H+E launch, deterministic per-block partials ----------
// partialH: [SBH][256] = [block][0..127 sum | 128..255 sumsq]
// partialE: [SBE][64]  = [block][0..31 sum  | 32..63 sumsq]
__global__ __launch_bounds__(256) void k_bnstats(const float* __restrict__ xh,
                                                 const unsigned short* __restrict__ xe,
                                                 float* __restrict__ partialH,
                                                 float* __restrict__ partialE) {
    int tid = threadIdx.x;
    if (blockIdx.x < SBH) {
        __shared__ float4 shs[256], shq[256];
        int c4 = (tid & 31) * 4;
        int r0 = tid >> 5;  // 0..7
        float4 s = make_float4(0.f, 0.f, 0.f, 0.f);
        float4 q = make_float4(0.f, 0.f, 0.f, 0.f);
        for (long r = (long)blockIdx.x * 8 + r0; r < NN; r += (long)SBH * 8) {
            float4 v = *(const float4*)(xh + r * D + c4);
            s.x += v.x; s.y += v.y; s.z += v.z; s.w += v.w;
            q.x += v.x * v.x; q.y += v.y * v.y; q.z += v.z * v.z; q.w += v.w * v.w;
        }
        shs[tid] = s;
        shq[tid] = q;
        __syncthreads();
        for (int st = 128; st >= 32; st >>= 1) {
            if (tid < st) {
                float4 a = shs[tid], b = shs[tid + st];
                a.x += b.x; a.y += b.y; a.z += b.z; a.w += b.w;
                shs[tid] = a;
                float4 c = shq[tid], d = shq[tid + st];
                c.x += d.x; c.y += d.y; c.z += d.z; c.w += d.w;
                shq[tid] = c;
            }
            __syncthreads();
        }
        if (tid < 32) {
            *(float4*)&partialH[(size_t)blockIdx.x * 256 + 4 * tid] = shs[tid];
            *(float4*)&partialH[(size_t)blockIdx.x * 256 + 128 + 4 * tid] = shq[tid];
        }
    } else {
        __shared__ float shs0[256], shs1[256], shq0[256], shq1[256];
        int blk = blockIdx.x - SBH;
        int d = tid & 15;
        int r0 = tid >> 4;  // 0..15
        float s0 = 0.f, s1 = 0.f, q0 = 0.f, q1 = 0.f;
        for (long r = (long)blk * 16 + r0; r < NE; r += (long)SBE * 16) {
            unsigned u = *(const unsigned*)(xe + r * HE + 2 * d);
            float a, b;
            unpk2(u, a, b);
            s0 += a; s1 += b;
            q0 += a * a; q1 += b * b;
        }
        shs0[tid] = s0; shs1[tid] = s1;
        shq0[tid] = q0; shq1[tid] = q1;
        __syncthreads();
        for (int st = 128; st >= 16; st >>= 1) {
            if (tid < st) {
                shs0[tid] += shs0[tid + st];
                shs1[tid] += shs1[tid + st];
                shq0[tid] += shq0[tid + st];
                shq1[tid] += shq1[tid + st];
            }
            __syncthreads();
        }
        if (tid < 16) {
            partialE[(size_t)blk * 64 + 2 * tid] = shs0[tid];
            partialE[(size_t)blk * 64 + 2 * tid + 1] = shs1[tid];
            partialE[(size_t)blk * 64 + 32 + 2 * tid] = shq0[tid];
            partialE[(size_t)blk * 64 + 32 + 2 * tid + 1] = shq1[tid];
        }
    }
}

// ---------- BN scale/shift prep: parallel deterministic tree reduce ----------
// grid 160 blocks: block f<128 -> H feature f; else E feature f-128
__global__ __launch_bounds__(256) void k_bnprep(const float* __restrict__ partialH,
                                                const float* __restrict__ gH,
                                                const float* __restrict__ bH,
                                                const float* __restrict__ partialE,
                                                const float* __restrict__ gE,
                                                const float* __restrict__ bE,
                                                float* __restrict__ scsh, int doE) {
    __shared__ float sh[512];
    int f = blockIdx.x;
    int tid = threadIdx.x;
    if (f < 128) {
        float s = 0.f, s2 = 0.f;
        for (int b = tid; b < SBH; b += 256) {
            s += partialH[(size_t)b * 256 + f];
            s2 += partialH[(size_t)b * 256 + 128 + f];
        }
        sh[tid] = s;
        sh[256 + tid] = s2;
        __syncthreads();
        for (int st = 128; st >= 1; st >>= 1) {
            if (tid < st) {
                sh[tid] += sh[tid + st];
                sh[256 + tid] += sh[256 + tid + st];
            }
            __syncthreads();
        }
        if (tid == 0) {
            float mu = sh[0] * (1.f / NN);
            float var = sh[256] * (1.f / NN) - mu * mu;
            float sc = rsqrtf(var + EPSV) * gH[f];
            scsh[f] = sc;
            scsh[128 + f] = bH[f] - mu * sc;
        }
    } else {
        if (!doE) return;
        int k = f - 128;
        float s = 0.f, s2 = 0.f;
        for (int b = tid; b < SBE; b += 256) {
            s += partialE[(size_t)b * 64 + k];
            s2 += partialE[(size_t)b * 64 + 32 + k];
        }
        sh[tid] = s;
        sh[256 + tid] = s2;
        __syncthreads();
        for (int st = 128; st >= 1; st >>= 1) {
            if (tid < st) {
                sh[tid] += sh[tid + st];
                sh[256 + tid] += sh[256 + tid + st];
            }
            __syncthreads();
        }
        if (tid == 0) {
            float mu = sh[0] * (1.f / NE);
            float var = sh[256] * (1.f / NE) - mu * mu;
            float sc = rsqrtf(var + EPSV) * gE[k];
            scsh[256 + k] = sc;
            scsh[288 + k] = bE[k] - mu * sc;
        }
    }
}

// ---------- out = lrelu(BN(h)) @ Wfc + bfc ----------
__global__ void k_out(const float* __restrict__ h, const float* __restrict__ scsh,
                      const float* __restrict__ Wfc, const float* __restrict__ bfc,
                      float* __restrict__ out) {
    int n = blockIdx.x * blockDim.x + threadIdx.x;
    if (n >= NN) return;
    const float* hr = h + (size_t)n * D;
    float s = bfc[0];
    for (int d = 0; d < D; d++) {
        float v = lrelu(hr[d] * scsh[d] + scsh[128 + d]);
        s += v * Wfc[d];
    }
    out[n] = s;
}

extern "C" void kernel_launch(void* const* d_in, const int* in_sizes, int n_in,
                              void* d_out, int out_size, void* d_ws, size_t ws_size,
                              hipStream_t stream) {
    const int* seq = (const int*)d_in[0];
    const int* sec = (const int*)d_in[1];
    const float* edge_p = (const float*)d_in[2];
    const int* src = (const int*)d_in[3];
    const int* dst = (const int*)d_in[4];
    const float* Wseq = (const float*)d_in[5];
    const float* Wsec = (const float*)d_in[6];
    const float* W0_node = (const float*)d_in[7];
    const float* b0_node = (const float*)d_in[8];
    const float* W0_ni = (const float*)d_in[9];
    const float* W0_fij = (const float*)d_in[10];
    const float* W0_nj = (const float*)d_in[11];
    const float* attn0 = (const float*)d_in[12];
    const float* ebias0 = (const float*)d_in[13];
    const float* Wn = (const float*)d_in[14];
    const float* bn = (const float*)d_in[15];
    const float* Wni = (const float*)d_in[16];
    const float* Wfij = (const float*)d_in[17];
    const float* Wnj = (const float*)d_in[18];
    const float* attnB = (const float*)d_in[19];
    const float* ebiasB = (const float*)d_in[20];
    const float* gn = (const float*)d_in[21];
    const float* betan = (const float*)d_in[22];
    const float* ge = (const float*)d_in[23];
    const float* betae = (const float*)d_in[24];
    const float* Wfc = (const float*)d_in[25];
    const float* bfc = (const float*)d_in[26];

    char* p = (char*)d_ws;
    auto alloc = [&](size_t bytes) -> char* {
        char* r = p;
        p += (bytes + 255) & ~(size_t)255;
        return r;
    };
    float* hA = (float*)alloc((size_t)NN * D * 4);
    float* hB = (float*)alloc((size_t)NN * D * 4);
    unsigned short* hp = (unsigned short*)alloc((size_t)NN * D * 2);      // bf16
    unsigned short* ebuf = (unsigned short*)alloc((size_t)NE * HE * 2);   // bf16, in-place
    float* logits = (float*)alloc((size_t)NE * HEADS * 4);                // [H][NE] planes
    float2* minv = (float2*)alloc((size_t)HEADS * NN * 8);
    float* ni = (float*)alloc((size_t)NN * HE * 4);
    float* nj = (float*)alloc((size_t)NN * HE * 4);
    int* esort = (int*)alloc((size_t)NE * 4);
    int* src_s = (int*)alloc((size_t)NE * 4);
    int* dst_s = (int*)alloc((size_t)NE * 4);
    float* ep_s = (float*)alloc((size_t)NE * 4);
    int* cnt = (int*)alloc((size_t)NN * 4);
    int* cursor = (int*)alloc((size_t)NN * 4);
    int* indptr = (int*)alloc((size_t)(NN + 1) * 4);
    int* bsum = (int*)alloc(256 * 4);
    int* bscan = (int*)alloc(256 * 4);
    float* partialH = (float*)alloc((size_t)SBH * 256 * 4);
    float* partialE = (float*)alloc((size_t)SBE * 64 * 4);
    float* scsh0 = (float*)alloc(320 * 4);
    float* scsh1 = (float*)alloc(320 * 4);

    const int EB = (NE + 255) / 256;   // 3125
    const int NB64 = (NN + 63) / 64;   // 782

    // CSR build + deterministic segment order + permuted edge arrays
    hipMemsetAsync(cnt, 0, (size_t)NN * 4, stream);
    hipMemsetAsync(cursor, 0, (size_t)NN * 4, stream);
    k_init_h<<<NN, 128, 0, stream>>>(seq, sec, Wseq, Wsec, hB);
    k_count<<<EB, 256, 0, stream>>>(dst, cnt);
    k_bsum<<<256, 256, 0, stream>>>(cnt, bsum);
    k_bscan<<<1, 256, 0, stream>>>(bsum, bscan, indptr);
    k_bwrite<<<256, 256, 0, stream>>>(cnt, bscan, indptr);
    k_scatter<<<EB, 256, 0, stream>>>(dst, indptr, cursor, esort);
    k_sortseg<<<(NN + 255) / 256, 256, 0, stream>>>(indptr, esort);
    k_permute<<<EB, 256, 0, stream>>>(esort, src, dst, edge_p, src_s, dst_s, ep_s);

    // ---- layer 0 (heads = 1), no BN ----
    k_node<0><<<NB64, 256, 0, stream>>>(hB, scsh0, W0_node, b0_node, W0_ni, W0_nj, hp, ni, nj);
    k_edge0<<<EB, 256, 0, stream>>>(ep_s, src_s, dst_s, ni, nj, W0_fij, attn0, ebias0, ebuf,
                                    logits);
    k_smstat<1><<<(NN + 255) / 256, 256, 0, stream>>>(indptr, logits, minv);
    k_aggregate<1><<<(NN + 3) / 4, 256, 0, stream>>>(indptr, src_s, logits, minv, hp, hA);

    // ---- deep layers (input hA for l=0; ping-pong) ----
    for (int l = 0; l < DEPTH; l++) {
        const float* Wn_l = Wn + (size_t)l * D * D;
        const float* bn_l = bn + (size_t)l * D;
        const float* Wni_l = Wni + (size_t)l * D * HE;
        const float* Wfij_l = Wfij + (size_t)l * HE * HE;
        const float* Wnj_l = Wnj + (size_t)l * D * HE;
        const float* attn_l = attnB + (size_t)l * HE;
        const float* eb_l = ebiasB + (size_t)l * HE;
        float* scshPrev = (l & 1) ? scsh0 : scsh1;
        float* scshCur = (l & 1) ? scsh1 : scsh0;
        float* hIn = (l & 1) ? hB : hA;
        float* hOut = (l & 1) ? hA : hB;
        int doE = (l < DEPTH - 1) ? 1 : 0;

        if (l == 0)
            k_node<0><<<NB64, 256, 0, stream>>>(hIn, scshPrev, Wn_l, bn_l, Wni_l, Wnj_l, hp,
                                                ni, nj);
        else
            k_node<1><<<NB64, 256, 0, stream>>>(hIn, scshPrev, Wn_l, bn_l, Wni_l, Wnj_l, hp,
                                                ni, nj);

        if (l == 0)
            k_edgeB<1, 0><<<EB, 256, 0, stream>>>(ebuf, src_s, dst_s, ni, nj, Wfij_l, attn_l,
                                                  eb_l, scshPrev, ebuf, logits);
        else if (l == DEPTH - 1)
            k_edgeB<0, 1><<<EB, 256, 0, stream>>>(ebuf, src_s, dst_s, ni, nj, Wfij_l, attn_l,
                                                  eb_l, scshPrev, ebuf, logits);
        else
            k_edgeB<0, 0><<<EB, 256, 0, stream>>>(ebuf, src_s, dst_s, ni, nj, Wfij_l, attn_l,
                                                  eb_l, scshPrev, ebuf, logits);
        k_smstat<HEADS><<<(NN * HEADS + 255) / 256, 256, 0, stream>>>(indptr, logits, minv);
        k_aggregate<HEADS><<<(NN + 3) / 4, 256, 0, stream>>>(indptr, src_s, logits, minv, hp,
                                                             hOut);

        k_bnstats<<<SBH + (doE ? SBE : 0), 256, 0, stream>>>(hOut, ebuf, partialH, partialE);
        k_bnprep<<<160, 256, 0, stream>>>(partialH, gn + (size_t)l * D, betan + (size_t)l * D,
                                          partialE, ge + (size_t)l * HE, betae + (size_t)l * HE,
                                          scshCur, doE);
    }

    // final h is in hA (l=7 wrote hOut=hA); BN of layer 7 is in scsh1
    k_out<<<(NN + 255) / 256, 256, 0, stream>>>(hA, scsh1, Wfc, bfc, (float*)d_out);
}

// Round 14
// 1937.567 us; speedup vs baseline: 1.6697x; 1.0624x over previous
//
#include <hip/hip_runtime.h>

#define NN 50000
#define NE 800000
#define D 128
#define HE 32
#define HEADS 4
#define DEPTH 8
#define EPSV 1e-5f
#define SLOPE 0.01f
#define CHUNK 196  // 196*256 >= 50000
#define SBH 512    // H-stat blocks (fixed, deterministic reduce)
#define SBE 1024   // E-stat blocks

__device__ __forceinline__ float lrelu(float x) { return x > 0.f ? x : SLOPE * x; }

__device__ __forceinline__ float bf2f(unsigned short u) {
    union { float f; unsigned i; } c;
    c.i = ((unsigned)u) << 16;
    return c.f;
}
__device__ __forceinline__ unsigned short f2bf(float f) {
    union { float f; unsigned i; } c;
    c.f = f;
    unsigned r = c.i + 0x7FFFu + ((c.i >> 16) & 1u);  // RNE
    return (unsigned short)(r >> 16);
}
__device__ __forceinline__ unsigned pack2(float a, float b) {
    return (unsigned)f2bf(a) | ((unsigned)f2bf(b) << 16);
}
__device__ __forceinline__ void unpk2(unsigned u, float& a, float& b) {
    union { float f; unsigned i; } c;
    c.i = u << 16; a = c.f;
    c.i = u & 0xFFFF0000u; b = c.f;
}

// ---------- h init ----------
__global__ void k_init_h(const int* __restrict__ seq, const int* __restrict__ sec,
                         const float* __restrict__ Wseq, const float* __restrict__ Wsec,
                         float* __restrict__ h) {
    int n = blockIdx.x;
    int d = threadIdx.x;  // 128
    float v = (d < 96) ? Wseq[seq[n] * 96 + d] : Wsec[sec[n] * 32 + (d - 96)];
    h[(size_t)n * D + d] = v;
}

// ---------- CSR build ----------
__global__ void k_count(const int* __restrict__ dst, int* __restrict__ cnt) {
    int e = blockIdx.x * blockDim.x + threadIdx.x;
    if (e < NE) atomicAdd(&cnt[dst[e]], 1);
}

__global__ void k_bsum(const int* __restrict__ cnt, int* __restrict__ bsum) {
    __shared__ int sh[256];
    int b = blockIdx.x, tid = threadIdx.x;
    int idx = b * CHUNK + tid;
    int v = (tid < CHUNK && idx < NN) ? cnt[idx] : 0;
    sh[tid] = v;
    __syncthreads();
    for (int st = 128; st >= 1; st >>= 1) {
        if (tid < st) sh[tid] += sh[tid + st];
        __syncthreads();
    }
    if (tid == 0) bsum[b] = sh[0];
}

__global__ void k_bscan(const int* __restrict__ bsum, int* __restrict__ bscan,
                        int* __restrict__ indptr) {
    __shared__ int sh[256];
    int tid = threadIdx.x;
    int v = bsum[tid];
    sh[tid] = v;
    __syncthreads();
    for (int st = 1; st < 256; st <<= 1) {
        int t = (tid >= st) ? sh[tid - st] : 0;
        __syncthreads();
        sh[tid] += t;
        __syncthreads();
    }
    bscan[tid] = sh[tid] - v;  // exclusive
    if (tid == 255) indptr[NN] = sh[255];
}

__global__ void k_bwrite(const int* __restrict__ cnt, const int* __restrict__ bscan,
                         int* __restrict__ indptr) {
    __shared__ int sh[256];
    int b = blockIdx.x, tid = threadIdx.x;
    int idx = b * CHUNK + tid;
    int v = (tid < CHUNK && idx < NN) ? cnt[idx] : 0;
    sh[tid] = v;
    __syncthreads();
    for (int st = 1; st < 256; st <<= 1) {
        int t = (tid >= st) ? sh[tid - st] : 0;
        __syncthreads();
        sh[tid] += t;
        __syncthreads();
    }
    if (tid < CHUNK && idx < NN) indptr[idx] = bscan[b] + sh[tid] - v;
}

__global__ void k_scatter(const int* __restrict__ dst, const int* __restrict__ indptr,
                          int* __restrict__ cursor, int* __restrict__ esort) {
    int e = blockIdx.x * blockDim.x + threadIdx.x;
    if (e >= NE) return;
    int dn = dst[e];
    int pos = atomicAdd(&cursor[dn], 1);
    esort[indptr[dn] + pos] = e;
}

// ---------- deterministic segment order: sort each segment by edge id ----------
__global__ void k_sortseg(const int* __restrict__ indptr, int* __restrict__ esort) {
    int n = blockIdx.x * blockDim.x + threadIdx.x;
    if (n >= NN) return;
    int b = indptr[n], e = indptr[n + 1];
    for (int i = b + 1; i < e; i++) {
        int v = esort[i];
        int j = i - 1;
        while (j >= b && esort[j] > v) {
            esort[j + 1] = esort[j];
            j--;
        }
        esort[j + 1] = v;
    }
}

__global__ void k_permute(const int* __restrict__ esort, const int* __restrict__ src,
                          const int* __restrict__ dst, const float* __restrict__ edge_p,
                          int* __restrict__ src_s, int* __restrict__ dst_s,
                          float* __restrict__ ep_s) {
    int i = blockIdx.x * blockDim.x + threadIdx.x;
    if (i >= NE) return;
    int e = esort[i];
    src_s[i] = src[e];
    dst_s[i] = dst[e];
    ep_s[i] = edge_p[e];
}

// ---------- fused node kernel, W staged in LDS (double-buffered 8-row stages) ----------
template <int APPLY_BN>
__global__ __launch_bounds__(256) void k_node(
    const float* __restrict__ hin, const float* __restrict__ scsh,
    const float* __restrict__ Wn_, const float* __restrict__ bn_,
    const float* __restrict__ Wni_, const float* __restrict__ Wnj_,
    unsigned short* __restrict__ hp, float* __restrict__ ni, float* __restrict__ nj) {
    __shared__ float hs[64][132];
    __shared__ float wb[2][8][192];
    int tid = threadIdx.x;
    int n0 = blockIdx.x * 64;

    float4 wreg[2];
    int wf0 = tid, wf1 = tid + 256;
    auto wload = [&](int s) {
#pragma unroll
        for (int u = 0; u < 2; u++) {
            int f = (u == 0) ? wf0 : wf1;
            if (f < 384) {
                int rr = f / 48, c = (f % 48) * 4;
                int dd = s * 8 + rr;
                const float* sp;
                if (c < 128) sp = Wn_ + (size_t)dd * 128 + c;
                else if (c < 160) sp = Wni_ + (size_t)dd * 32 + (c - 128);
                else sp = Wnj_ + (size_t)dd * 32 + (c - 160);
                wreg[u] = *(const float4*)sp;
            }
        }
    };
    auto wstore = [&](int buf) {
#pragma unroll
        for (int u = 0; u < 2; u++) {
            int f = (u == 0) ? wf0 : wf1;
            if (f < 384) {
                int rr = f / 48, c = (f % 48) * 4;
                *(float4*)&wb[buf][rr][c] = wreg[u];
            }
        }
    };

    wload(0);
#pragma unroll
    for (int k = 0; k < 8; k++) {
        int f = tid + k * 256;
        int r = f >> 5, c4 = f & 31;
        int row = n0 + r;
        if (row >= NN) row = NN - 1;
        float4 v = *(const float4*)(hin + (size_t)row * D + c4 * 4);
        if (APPLY_BN) {
            float4 sc = *(const float4*)(scsh + c4 * 4);
            float4 sh = *(const float4*)(scsh + 128 + c4 * 4);
            v.x = lrelu(v.x * sc.x + sh.x);
            v.y = lrelu(v.y * sc.y + sh.y);
            v.z = lrelu(v.z * sc.z + sh.z);
            v.w = lrelu(v.w * sc.w + sh.w);
        }
        *(float4*)(&hs[r][c4 * 4]) = v;
    }
    wstore(0);
    __syncthreads();

    int rg = tid >> 4;  // 0..15
    int cg = tid & 15;  // 0..15
    int pcol = 128 + (cg & 7) * 4 + ((cg < 8) ? 0 : 32);
    float4 bA = *(const float4*)(bn_ + cg * 4);
    float4 bB = *(const float4*)(bn_ + 64 + cg * 4);
    float4 accA[4], accB[4], accC[4];
#pragma unroll
    for (int r = 0; r < 4; r++) {
        accA[r] = bA;
        accB[r] = bB;
        accC[r] = make_float4(0.f, 0.f, 0.f, 0.f);
    }

#define FMA4(acc_, hv_, w_)                                     \
    (acc_).x += (hv_) * (w_).x; (acc_).y += (hv_) * (w_).y;     \
    (acc_).z += (hv_) * (w_).z; (acc_).w += (hv_) * (w_).w;

    for (int s = 0; s < 16; s++) {
        int cur = s & 1;
        if (s < 15) wload(s + 1);
#pragma unroll
        for (int dd = 0; dd < 8; dd++) {
            int d = s * 8 + dd;
            float h0 = hs[rg * 4 + 0][d];
            float h1 = hs[rg * 4 + 1][d];
            float h2 = hs[rg * 4 + 2][d];
            float h3 = hs[rg * 4 + 3][d];
            float4 wv0 = *(const float4*)&wb[cur][dd][cg * 4];
            float4 wv1 = *(const float4*)&wb[cur][dd][64 + cg * 4];
            float4 wv2 = *(const float4*)&wb[cur][dd][pcol];
            FMA4(accA[0], h0, wv0) FMA4(accA[1], h1, wv0)
            FMA4(accA[2], h2, wv0) FMA4(accA[3], h3, wv0)
            FMA4(accB[0], h0, wv1) FMA4(accB[1], h1, wv1)
            FMA4(accB[2], h2, wv1) FMA4(accB[3], h3, wv1)
            FMA4(accC[0], h0, wv2) FMA4(accC[1], h1, wv2)
            FMA4(accC[2], h2, wv2) FMA4(accC[3], h3, wv2)
        }
        __syncthreads();
        if (s < 15) {
            wstore((s + 1) & 1);
            __syncthreads();
        }
    }

    float* projOut = (cg < 8) ? ni : nj;
    int pc = (cg & 7) * 4;
#pragma unroll
    for (int r = 0; r < 4; r++) {
        int row = n0 + rg * 4 + r;
        if (row < NN) {
            ushort4 pa = make_ushort4(f2bf(accA[r].x), f2bf(accA[r].y), f2bf(accA[r].z),
                                      f2bf(accA[r].w));
            ushort4 pb = make_ushort4(f2bf(accB[r].x), f2bf(accB[r].y), f2bf(accB[r].z),
                                      f2bf(accB[r].w));
            *(ushort4*)(hp + (size_t)row * D + cg * 4) = pa;
            *(ushort4*)(hp + (size_t)row * D + 64 + cg * 4) = pb;
            *(float4*)(projOut + (size_t)row * HE + pc) = accC[r];
        }
    }
}

// ---------- layer-0 edge kernel (heads=1, e = scalar edge_p) ----------
__global__ __launch_bounds__(256) void k_edge0(
    const float* __restrict__ ep_s, const int* __restrict__ src_s,
    const int* __restrict__ dst_s, const float* __restrict__ ni,
    const float* __restrict__ nj, const float* __restrict__ Wfij,
    const float* __restrict__ attn, const float* __restrict__ ebias,
    unsigned short* __restrict__ fout, float* __restrict__ logits) {
    __shared__ float sw[HE], sa[HE], se[HE];
    int tid = threadIdx.x;
    if (tid < HE) {
        sw[tid] = Wfij[tid];
        sa[tid] = attn[tid];
        se[tid] = ebias[tid];
    }
    __syncthreads();
    int i = blockIdx.x * blockDim.x + tid;
    if (i >= NE) return;
    int sn = src_s[i], dn = dst_s[i];
    float p = ep_s[i];
    const float4* niv = (const float4*)(ni + (size_t)sn * HE);
    const float4* njv = (const float4*)(nj + (size_t)dn * HE);
    float acc[HE];
#pragma unroll
    for (int j = 0; j < 8; j++) {
        float4 a = niv[j];
        float4 b = njv[j];
        acc[4 * j + 0] = se[4 * j + 0] + p * sw[4 * j + 0] + a.x + b.x;
        acc[4 * j + 1] = se[4 * j + 1] + p * sw[4 * j + 1] + a.y + b.y;
        acc[4 * j + 2] = se[4 * j + 2] + p * sw[4 * j + 2] + a.z + b.z;
        acc[4 * j + 3] = se[4 * j + 3] + p * sw[4 * j + 3] + a.w + b.w;
    }
    float lg = 0.f;
#pragma unroll
    for (int k = 0; k < HE; k++) {
        acc[k] = lrelu(acc[k]);
        lg += acc[k] * sa[k];
    }
    uint4* fo = (uint4*)(fout + (size_t)i * HE);
#pragma unroll
    for (int j = 0; j < 4; j++) {
        uint4 v;
        v.x = pack2(acc[8 * j + 0], acc[8 * j + 1]);
        v.y = pack2(acc[8 * j + 2], acc[8 * j + 3]);
        v.z = pack2(acc[8 * j + 4], acc[8 * j + 5]);
        v.w = pack2(acc[8 * j + 6], acc[8 * j + 7]);
        fo[j] = v;
    }
    logits[i] = lg;
}

// ---------- deep edge kernel: 2 edges/thread, k split in halves of 16 ----------
template <int FIRST, int LAST>
__global__ __launch_bounds__(256) void k_edgeB(
    const unsigned short* __restrict__ e_in, const int* __restrict__ src_s,
    const int* __restrict__ dst_s, const float* __restrict__ ni,
    const float* __restrict__ nj, const float* __restrict__ Wfij,
    const float* __restrict__ attn, const float* __restrict__ ebias,
    const float* __restrict__ scsh,  // [256..287]=scaleE, [288..319]=shiftE (prev layer)
    unsigned short* __restrict__ fout, float* __restrict__ logits) {
    int tid = threadIdx.x;
    int i0 = blockIdx.x * 512 + tid;
    if (i0 >= NE) return;
    int i1 = i0 + 256;
    bool v1 = i1 < NE;
    int i1s = v1 ? i1 : i0;
    int sn0 = src_s[i0], dn0 = dst_s[i0];
    int sn1 = src_s[i1s], dn1 = dst_s[i1s];
    const uint4* ein0 = (const uint4*)(e_in + (size_t)i0 * HE);
    const uint4* ein1 = (const uint4*)(e_in + (size_t)i1s * HE);

    for (int half = 0; half < 2; half++) {
        int k0 = half * 16;
        float acc0[16], acc1[16];
        {
            const float4* a0 = (const float4*)(ni + (size_t)sn0 * HE + k0);
            const float4* b0 = (const float4*)(nj + (size_t)dn0 * HE + k0);
            const float4* a1 = (const float4*)(ni + (size_t)sn1 * HE + k0);
            const float4* b1 = (const float4*)(nj + (size_t)dn1 * HE + k0);
            const float4* eb4 = (const float4*)(ebias + k0);
#pragma unroll
            for (int j4 = 0; j4 < 4; j4++) {
                float4 va0 = a0[j4], vb0 = b0[j4];
                float4 va1 = a1[j4], vb1 = b1[j4];
                float4 eb = eb4[j4];
                acc0[4 * j4 + 0] = eb.x + va0.x + vb0.x;
                acc0[4 * j4 + 1] = eb.y + va0.y + vb0.y;
                acc0[4 * j4 + 2] = eb.z + va0.z + vb0.z;
                acc0[4 * j4 + 3] = eb.w + va0.w + vb0.w;
                acc1[4 * j4 + 0] = eb.x + va1.x + vb1.x;
                acc1[4 * j4 + 1] = eb.y + va1.y + vb1.y;
                acc1[4 * j4 + 2] = eb.z + va1.z + vb1.z;
                acc1[4 * j4 + 3] = eb.w + va1.w + vb1.w;
            }
        }
#pragma unroll
        for (int j = 0; j < 4; j++) {
            uint4 ev0 = ein0[j];
            uint4 ev1 = ein1[j];
            float ec0[8], ec1[8];
            unpk2(ev0.x, ec0[0], ec0[1]); unpk2(ev0.y, ec0[2], ec0[3]);
            unpk2(ev0.z, ec0[4], ec0[5]); unpk2(ev0.w, ec0[6], ec0[7]);
            unpk2(ev1.x, ec1[0], ec1[1]); unpk2(ev1.y, ec1[2], ec1[3]);
            unpk2(ev1.z, ec1[4], ec1[5]); unpk2(ev1.w, ec1[6], ec1[7]);
#pragma unroll
            for (int c = 0; c < 8; c++) {
                int de = 8 * j + c;
                float x0 = ec0[c], x1 = ec1[c];
                if (!FIRST) {
                    float sc = scsh[256 + de], sh = scsh[288 + de];
                    x0 = lrelu(x0 * sc + sh);
                    x1 = lrelu(x1 * sc + sh);
                }
                const float4* wr = (const float4*)(Wfij + (size_t)de * HE + k0);
#pragma unroll
                for (int k4 = 0; k4 < 4; k4++) {
                    float4 w = wr[k4];
                    acc0[4 * k4 + 0] += x0 * w.x; acc1[4 * k4 + 0] += x1 * w.x;
                    acc0[4 * k4 + 1] += x0 * w.y; acc1[4 * k4 + 1] += x1 * w.y;
                    acc0[4 * k4 + 2] += x0 * w.z; acc1[4 * k4 + 2] += x1 * w.z;
                    acc0[4 * k4 + 3] += x0 * w.w; acc1[4 * k4 + 3] += x1 * w.w;
                }
            }
        }
#pragma unroll
        for (int k = 0; k < 16; k++) {
            acc0[k] = lrelu(acc0[k]);
            acc1[k] = lrelu(acc1[k]);
        }
        if (!LAST) {
            uint4 v0a, v0b;
            v0a.x = pack2(acc0[0], acc0[1]);  v0a.y = pack2(acc0[2], acc0[3]);
            v0a.z = pack2(acc0[4], acc0[5]);  v0a.w = pack2(acc0[6], acc0[7]);
            v0b.x = pack2(acc0[8], acc0[9]);  v0b.y = pack2(acc0[10], acc0[11]);
            v0b.z = pack2(acc0[12], acc0[13]); v0b.w = pack2(acc0[14], acc0[15]);
            *(uint4*)(fout + (size_t)i0 * HE + k0) = v0a;
            *(uint4*)(fout + (size_t)i0 * HE + k0 + 8) = v0b;
            if (v1) {
                uint4 v1a, v1b;
                v1a.x = pack2(acc1[0], acc1[1]);  v1a.y = pack2(acc1[2], acc1[3]);
                v1a.z = pack2(acc1[4], acc1[5]);  v1a.w = pack2(acc1[6], acc1[7]);
                v1b.x = pack2(acc1[8], acc1[9]);  v1b.y = pack2(acc1[10], acc1[11]);
                v1b.z = pack2(acc1[12], acc1[13]); v1b.w = pack2(acc1[14], acc1[15]);
                *(uint4*)(fout + (size_t)i1 * HE + k0) = v1a;
                *(uint4*)(fout + (size_t)i1 * HE + k0 + 8) = v1b;
            }
        }
#pragma unroll
        for (int hh2 = 0; hh2 < 2; hh2++) {
            int hh = half * 2 + hh2;
            float s0 = 0.f, s1 = 0.f;
#pragma unroll
            for (int j = 0; j < 8; j++) {
                float av = attn[hh * 8 + j];
                s0 += acc0[hh2 * 8 + j] * av;
                s1 += acc1[hh2 * 8 + j] * av;
            }
            logits[(size_t)hh * NE + i0] = s0;
            if (v1) logits[(size_t)hh * NE + i1] = s1;
        }
    }
}

// ---------- fused softmax-stats + aggregate: wave per node ----------
// phase 1: per-head m, 1/sum via 16-lane strided partial + shfl_xor tree (deterministic)
// phase 2: gather with w = exp(l-m)*inv inline
template <int H>
__global__ __launch_bounds__(256) void k_aggsm(const int* __restrict__ indptr,
                                               const int* __restrict__ src_s,
                                               const float* __restrict__ logits,
                                               const unsigned short* __restrict__ hp,
                                               float* __restrict__ hacc) {
    int n = blockIdx.x * 4 + (threadIdx.x >> 6);
    if (n >= NN) return;
    int lane = threadIdx.x & 63;
    int c2 = lane * 2;  // cols c2, c2+1
    int b = indptr[n], e = indptr[n + 1];
    int hh = (H == 1) ? 0 : (lane >> 4);
    const float* lp = logits + (size_t)hh * NE;
    const int stride = (H == 1) ? 64 : 16;
    int sub = (H == 1) ? lane : (lane & 15);
    float m = -1e30f;
    for (int i = b + sub; i < e; i += stride) m = fmaxf(m, lp[i]);
#pragma unroll
    for (int w = 32; w >= 1; w >>= 1)
        if (w < stride) m = fmaxf(m, __shfl_xor(m, w));
    float s = 0.f;
    for (int i = b + sub; i < e; i += stride) s += __expf(lp[i] - m);
#pragma unroll
    for (int w = 32; w >= 1; w >>= 1)
        if (w < stride) s += __shfl_xor(s, w);
    float inv = (e > b) ? 1.f / s : 0.f;
    float acc0 = 0.f, acc1 = 0.f;
#pragma unroll 4
    for (int i = b; i < e; i++) {
        float w = __expf(lp[i] - m) * inv;
        unsigned u = *(const unsigned*)(hp + (size_t)src_s[i] * D + c2);
        float x0, x1;
        unpk2(u, x0, x1);
        acc0 += w * x0;
        acc1 += w * x1;
    }
    *(float2*)(hacc + (size_t)n * D + c2) = make_float2(acc0, acc1);
}

// ---------- BN stats, merged H+E launch, deterministic per-block partials ----------
__global__ __launch_bounds__(256) void k_bnstats(const float* __restrict__ xh,
                                                 const unsigned short* __restrict__ xe,
                                                 float* __restrict__ partialH,
                                                 float* __restrict__ partialE) {
    int tid = threadIdx.x;
    if (blockIdx.x < SBH) {
        __shared__ float4 shs[256], shq[256];
        int c4 = (tid & 31) * 4;
        int r0 = tid >> 5;  // 0..7
        float4 s = make_float4(0.f, 0.f, 0.f, 0.f);
        float4 q = make_float4(0.f, 0.f, 0.f, 0.f);
        for (long r = (long)blockIdx.x * 8 + r0; r < NN; r += (long)SBH * 8) {
            float4 v = *(const float4*)(xh + r * D + c4);
            s.x += v.x; s.y += v.y; s.z += v.z; s.w += v.w;
            q.x += v.x * v.x; q.y += v.y * v.y; q.z += v.z * v.z; q.w += v.w * v.w;
        }
        shs[tid] = s;
        shq[tid] = q;
        __syncthreads();
        for (int st = 128; st >= 32; st >>= 1) {
            if (tid < st) {
                float4 a = shs[tid], b = shs[tid + st];
                a.x += b.x; a.y += b.y; a.z += b.z; a.w += b.w;
                shs[tid] = a;
                float4 c = shq[tid], d = shq[tid + st];
                c.x += d.x; c.y += d.y; c.z += d.z; c.w += d.w;
                shq[tid] = c;
            }
            __syncthreads();
        }
        if (tid < 32) {
            *(float4*)&partialH[(size_t)blockIdx.x * 256 + 4 * tid] = shs[tid];
            *(float4*)&partialH[(size_t)blockIdx.x * 256 + 128 + 4 * tid] = shq[tid];
        }
    } else {
        __shared__ float shs0[256], shs1[256], shq0[256], shq1[256];
        int blk = blockIdx.x - SBH;
        int d = tid & 15;
        int r0 = tid >> 4;  // 0..15
        float s0 = 0.f, s1 = 0.f, q0 = 0.f, q1 = 0.f;
        for (long r = (long)blk * 16 + r0; r < NE; r += (long)SBE * 16) {
            unsigned u = *(const unsigned*)(xe + r * HE + 2 * d);
            float a, b;
            unpk2(u, a, b);
            s0 += a; s1 += b;
            q0 += a * a; q1 += b * b;
        }
        shs0[tid] = s0; shs1[tid] = s1;
        shq0[tid] = q0; shq1[tid] = q1;
        __syncthreads();
        for (int st = 128; st >= 16; st >>= 1) {
            if (tid < st) {
                shs0[tid] += shs0[tid + st];
                shs1[tid] += shs1[tid + st];
                shq0[tid] += shq0[tid + st];
                shq1[tid] += shq1[tid + st];
            }
            __syncthreads();
        }
        if (tid < 16) {
            partialE[(size_t)blk * 64 + 2 * tid] = shs0[tid];
            partialE[(size_t)blk * 64 + 2 * tid + 1] = shs1[tid];
            partialE[(size_t)blk * 64 + 32 + 2 * tid] = shq0[tid];
            partialE[(size_t)blk * 64 + 32 + 2 * tid + 1] = shq1[tid];
        }
    }
}

// ---------- BN scale/shift prep: parallel deterministic tree reduce ----------
__global__ __launch_bounds__(256) void k_bnprep(const float* __restrict__ partialH,
                                                const float* __restrict__ gH,
                                                const float* __restrict__ bH,
                                                const float* __restrict__ partialE,
                                                const float* __restrict__ gE,
                                                const float* __restrict__ bE,
                                                float* __restrict__ scsh, int doE) {
    __shared__ float sh[512];
    int f = blockIdx.x;
    int tid = threadIdx.x;
    if (f < 128) {
        float s = 0.f, s2 = 0.f;
        for (int b = tid; b < SBH; b += 256) {
            s += partialH[(size_t)b * 256 + f];
            s2 += partialH[(size_t)b * 256 + 128 + f];
        }
        sh[tid] = s;
        sh[256 + tid] = s2;
        __syncthreads();
        for (int st = 128; st >= 1; st >>= 1) {
            if (tid < st) {
                sh[tid] += sh[tid + st];
                sh[256 + tid] += sh[256 + tid + st];
            }
            __syncthreads();
        }
        if (tid == 0) {
            float mu = sh[0] * (1.f / NN);
            float var = sh[256] * (1.f / NN) - mu * mu;
            float sc = rsqrtf(var + EPSV) * gH[f];
            scsh[f] = sc;
            scsh[128 + f] = bH[f] - mu * sc;
        }
    } else {
        if (!doE) return;
        int k = f - 128;
        float s = 0.f, s2 = 0.f;
        for (int b = tid; b < SBE; b += 256) {
            s += partialE[(size_t)b * 64 + k];
            s2 += partialE[(size_t)b * 64 + 32 + k];
        }
        sh[tid] = s;
        sh[256 + tid] = s2;
        __syncthreads();
        for (int st = 128; st >= 1; st >>= 1) {
            if (tid < st) {
                sh[tid] += sh[tid + st];
                sh[256 + tid] += sh[256 + tid + st];
            }
            __syncthreads();
        }
        if (tid == 0) {
            float mu = sh[0] * (1.f / NE);
            float var = sh[256] * (1.f / NE) - mu * mu;
            float sc = rsqrtf(var + EPSV) * gE[k];
            scsh[256 + k] = sc;
            scsh[288 + k] = bE[k] - mu * sc;
        }
    }
}

// ---------- out = lrelu(BN(h)) @ Wfc + bfc ----------
__global__ void k_out(const float* __restrict__ h, const float* __restrict__ scsh,
                      const float* __restrict__ Wfc, const float* __restrict__ bfc,
                      float* __restrict__ out) {
    int n = blockIdx.x * blockDim.x + threadIdx.x;
    if (n >= NN) return;
    const float* hr = h + (size_t)n * D;
    float s = bfc[0];
    for (int d = 0; d < D; d++) {
        float v = lrelu(hr[d] * scsh[d] + scsh[128 + d]);
        s += v * Wfc[d];
    }
    out[n] = s;
}

extern "C" void kernel_launch(void* const* d_in, const int* in_sizes, int n_in,
                              void* d_out, int out_size, void* d_ws, size_t ws_size,
                              hipStream_t stream) {
    const int* seq = (const int*)d_in[0];
    const int* sec = (const int*)d_in[1];
    const float* edge_p = (const float*)d_in[2];
    const int* src = (const int*)d_in[3];
    const int* dst = (const int*)d_in[4];
    const float* Wseq = (const float*)d_in[5];
    const float* Wsec = (const float*)d_in[6];
    const float* W0_node = (const float*)d_in[7];
    const float* b0_node = (const float*)d_in[8];
    const float* W0_ni = (const float*)d_in[9];
    const float* W0_fij = (const float*)d_in[10];
    const float* W0_nj = (const float*)d_in[11];
    const float* attn0 = (const float*)d_in[12];
    const float* ebias0 = (const float*)d_in[13];
    const float* Wn = (const float*)d_in[14];
    const float* bn = (const float*)d_in[15];
    const float* Wni = (const float*)d_in[16];
    const float* Wfij = (const float*)d_in[17];
    const float* Wnj = (const float*)d_in[18];
    const float* attnB = (const float*)d_in[19];
    const float* ebiasB = (const float*)d_in[20];
    const float* gn = (const float*)d_in[21];
    const float* betan = (const float*)d_in[22];
    const float* ge = (const float*)d_in[23];
    const float* betae = (const float*)d_in[24];
    const float* Wfc = (const float*)d_in[25];
    const float* bfc = (const float*)d_in[26];

    char* p = (char*)d_ws;
    auto alloc = [&](size_t bytes) -> char* {
        char* r = p;
        p += (bytes + 255) & ~(size_t)255;
        return r;
    };
    float* hA = (float*)alloc((size_t)NN * D * 4);
    float* hB = (float*)alloc((size_t)NN * D * 4);
    unsigned short* hp = (unsigned short*)alloc((size_t)NN * D * 2);      // bf16
    unsigned short* ebuf = (unsigned short*)alloc((size_t)NE * HE * 2);   // bf16, in-place
    float* logits = (float*)alloc((size_t)NE * HEADS * 4);                // [H][NE] planes
    float* ni = (float*)alloc((size_t)NN * HE * 4);
    float* nj = (float*)alloc((size_t)NN * HE * 4);
    int* esort = (int*)alloc((size_t)NE * 4);
    int* src_s = (int*)alloc((size_t)NE * 4);
    int* dst_s = (int*)alloc((size_t)NE * 4);
    float* ep_s = (float*)alloc((size_t)NE * 4);
    int* cnt = (int*)alloc((size_t)NN * 4);
    int* cursor = (int*)alloc((size_t)NN * 4);
    int* indptr = (int*)alloc((size_t)(NN + 1) * 4);
    int* bsum = (int*)alloc(256 * 4);
    int* bscan = (int*)alloc(256 * 4);
    float* partialH = (float*)alloc((size_t)SBH * 256 * 4);
    float* partialE = (float*)alloc((size_t)SBE * 64 * 4);
    float* scsh0 = (float*)alloc(320 * 4);
    float* scsh1 = (float*)alloc(320 * 4);

    const int EB = (NE + 255) / 256;    // 3125
    const int EB2 = (NE + 511) / 512;   // 1563
    const int NB64 = (NN + 63) / 64;    // 782

    // CSR build + deterministic segment order + permuted edge arrays
    hipMemsetAsync(cnt, 0, (size_t)NN * 4, stream);
    hipMemsetAsync(cursor, 0, (size_t)NN * 4, stream);
    k_init_h<<<NN, 128, 0, stream>>>(seq, sec, Wseq, Wsec, hB);
    k_count<<<EB, 256, 0, stream>>>(dst, cnt);
    k_bsum<<<256, 256, 0, stream>>>(cnt, bsum);
    k_bscan<<<1, 256, 0, stream>>>(bsum, bscan, indptr);
    k_bwrite<<<256, 256, 0, stream>>>(cnt, bscan, indptr);
    k_scatter<<<EB, 256, 0, stream>>>(dst, indptr, cursor, esort);
    k_sortseg<<<(NN + 255) / 256, 256, 0, stream>>>(indptr, esort);
    k_permute<<<EB, 256, 0, stream>>>(esort, src, dst, edge_p, src_s, dst_s, ep_s);

    // ---- layer 0 (heads = 1), no BN ----
    k_node<0><<<NB64, 256, 0, stream>>>(hB, scsh0, W0_node, b0_node, W0_ni, W0_nj, hp, ni, nj);
    k_edge0<<<EB, 256, 0, stream>>>(ep_s, src_s, dst_s, ni, nj, W0_fij, attn0, ebias0, ebuf,
                                    logits);
    k_aggsm<1><<<(NN + 3) / 4, 256, 0, stream>>>(indptr, src_s, logits, hp, hA);

    // ---- deep layers (input hA for l=0; ping-pong) ----
    for (int l = 0; l < DEPTH; l++) {
        const float* Wn_l = Wn + (size_t)l * D * D;
        const float* bn_l = bn + (size_t)l * D;
        const float* Wni_l = Wni + (size_t)l * D * HE;
        const float* Wfij_l = Wfij + (size_t)l * HE * HE;
        const float* Wnj_l = Wnj + (size_t)l * D * HE;
        const float* attn_l = attnB + (size_t)l * HE;
        const float* eb_l = ebiasB + (size_t)l * HE;
        float* scshPrev = (l & 1) ? scsh0 : scsh1;
        float* scshCur = (l & 1) ? scsh1 : scsh0;
        float* hIn = (l & 1) ? hB : hA;
        float* hOut = (l & 1) ? hA : hB;
        int doE = (l < DEPTH - 1) ? 1 : 0;

        if (l == 0)
            k_node<0><<<NB64, 256, 0, stream>>>(hIn, scshPrev, Wn_l, bn_l, Wni_l, Wnj_l, hp,
                                                ni, nj);
        else
            k_node<1><<<NB64, 256, 0, stream>>>(hIn, scshPrev, Wn_l, bn_l, Wni_l, Wnj_l, hp,
                                                ni, nj);

        if (l == 0)
            k_edgeB<1, 0><<<EB2, 256, 0, stream>>>(ebuf, src_s, dst_s, ni, nj, Wfij_l, attn_l,
                                                   eb_l, scshPrev, ebuf, logits);
        else if (l == DEPTH - 1)
            k_edgeB<0, 1><<<EB2, 256, 0, stream>>>(ebuf, src_s, dst_s, ni, nj, Wfij_l, attn_l,
                                                   eb_l, scshPrev, ebuf, logits);
        else
            k_edgeB<0, 0><<<EB2, 256, 0, stream>>>(ebuf, src_s, dst_s, ni, nj, Wfij_l, attn_l,
                                                   eb_l, scshPrev, ebuf, logits);
        k_aggsm<HEADS><<<(NN + 3) / 4, 256, 0, stream>>>(indptr, src_s, logits, hp, hOut);

        k_bnstats<<<SBH + (doE ? SBE : 0), 256, 0, stream>>>(hOut, ebuf, partialH, partialE);
        k_bnprep<<<160, 256, 0, stream>>>(partialH, gn + (size_t)l * D, betan + (size_t)l * D,
                                          partialE, ge + (size_t)l * HE, betae + (size_t)l * HE,
                                          scshCur, doE);
    }

    // final h is in hA (l=7 wrote hOut=hA); BN of layer 7 is in scsh1
    k_out<<<(NN + 255) / 256, 256, 0, stream>>>(hA, scsh1, Wfc, bfc, (float*)d_out);
}

// Round 15
// 1889.181 us; speedup vs baseline: 1.7124x; 1.0256x over previous
//
#include <hip/hip_runtime.h>

#define NN 50000
#define NE 800000
#define D 128
#define HE 32
#define HEADS 4
#define DEPTH 8
#define EPSV 1e-5f
#define SLOPE 0.01f
#define CHUNK 196  // 196*256 >= 50000
#define SBH 512    // H-stat blocks (fixed, deterministic reduce)
#define SBE 1024   // E-stat blocks

__device__ __forceinline__ float lrelu(float x) { return x > 0.f ? x : SLOPE * x; }

__device__ __forceinline__ float bf2f(unsigned short u) {
    union { float f; unsigned i; } c;
    c.i = ((unsigned)u) << 16;
    return c.f;
}
__device__ __forceinline__ unsigned short f2bf(float f) {
    union { float f; unsigned i; } c;
    c.f = f;
    unsigned r = c.i + 0x7FFFu + ((c.i >> 16) & 1u);  // RNE
    return (unsigned short)(r >> 16);
}
__device__ __forceinline__ unsigned pack2(float a, float b) {
    return (unsigned)f2bf(a) | ((unsigned)f2bf(b) << 16);
}
__device__ __forceinline__ void unpk2(unsigned u, float& a, float& b) {
    union { float f; unsigned i; } c;
    c.i = u << 16; a = c.f;
    c.i = u & 0xFFFF0000u; b = c.f;
}

// ---------- h init ----------
__global__ void k_init_h(const int* __restrict__ seq, const int* __restrict__ sec,
                         const float* __restrict__ Wseq, const float* __restrict__ Wsec,
                         float* __restrict__ h) {
    int n = blockIdx.x;
    int d = threadIdx.x;  // 128
    float v = (d < 96) ? Wseq[seq[n] * 96 + d] : Wsec[sec[n] * 32 + (d - 96)];
    h[(size_t)n * D + d] = v;
}

// ---------- CSR build ----------
__global__ void k_count(const int* __restrict__ dst, int* __restrict__ cnt) {
    int e = blockIdx.x * blockDim.x + threadIdx.x;
    if (e < NE) atomicAdd(&cnt[dst[e]], 1);
}

__global__ void k_bsum(const int* __restrict__ cnt, int* __restrict__ bsum) {
    __shared__ int sh[256];
    int b = blockIdx.x, tid = threadIdx.x;
    int idx = b * CHUNK + tid;
    int v = (tid < CHUNK && idx < NN) ? cnt[idx] : 0;
    sh[tid] = v;
    __syncthreads();
    for (int st = 128; st >= 1; st >>= 1) {
        if (tid < st) sh[tid] += sh[tid + st];
        __syncthreads();
    }
    if (tid == 0) bsum[b] = sh[0];
}

__global__ void k_bscan(const int* __restrict__ bsum, int* __restrict__ bscan,
                        int* __restrict__ indptr) {
    __shared__ int sh[256];
    int tid = threadIdx.x;
    int v = bsum[tid];
    sh[tid] = v;
    __syncthreads();
    for (int st = 1; st < 256; st <<= 1) {
        int t = (tid >= st) ? sh[tid - st] : 0;
        __syncthreads();
        sh[tid] += t;
        __syncthreads();
    }
    bscan[tid] = sh[tid] - v;  // exclusive
    if (tid == 255) indptr[NN] = sh[255];
}

__global__ void k_bwrite(const int* __restrict__ cnt, const int* __restrict__ bscan,
                         int* __restrict__ indptr) {
    __shared__ int sh[256];
    int b = blockIdx.x, tid = threadIdx.x;
    int idx = b * CHUNK + tid;
    int v = (tid < CHUNK && idx < NN) ? cnt[idx] : 0;
    sh[tid] = v;
    __syncthreads();
    for (int st = 1; st < 256; st <<= 1) {
        int t = (tid >= st) ? sh[tid - st] : 0;
        __syncthreads();
        sh[tid] += t;
        __syncthreads();
    }
    if (tid < CHUNK && idx < NN) indptr[idx] = bscan[b] + sh[tid] - v;
}

__global__ void k_scatter(const int* __restrict__ dst, const int* __restrict__ indptr,
                          int* __restrict__ cursor, int* __restrict__ esort) {
    int e = blockIdx.x * blockDim.x + threadIdx.x;
    if (e >= NE) return;
    int dn = dst[e];
    int pos = atomicAdd(&cursor[dn], 1);
    esort[indptr[dn] + pos] = e;
}

// ---------- deterministic segment order: sort each segment by edge id ----------
__global__ void k_sortseg(const int* __restrict__ indptr, int* __restrict__ esort) {
    int n = blockIdx.x * blockDim.x + threadIdx.x;
    if (n >= NN) return;
    int b = indptr[n], e = indptr[n + 1];
    for (int i = b + 1; i < e; i++) {
        int v = esort[i];
        int j = i - 1;
        while (j >= b && esort[j] > v) {
            esort[j + 1] = esort[j];
            j--;
        }
        esort[j + 1] = v;
    }
}

__global__ void k_permute(const int* __restrict__ esort, const int* __restrict__ src,
                          const int* __restrict__ dst, const float* __restrict__ edge_p,
                          int* __restrict__ src_s, int* __restrict__ dst_s,
                          float* __restrict__ ep_s) {
    int i = blockIdx.x * blockDim.x + threadIdx.x;
    if (i >= NE) return;
    int e = esort[i];
    src_s[i] = src[e];
    dst_s[i] = dst[e];
    ep_s[i] = edge_p[e];
}

// ---------- fused node kernel, W staged in LDS (double-buffered 8-row stages) ----------
template <int APPLY_BN>
__global__ __launch_bounds__(256) void k_node(
    const float* __restrict__ hin, const float* __restrict__ scsh,
    const float* __restrict__ Wn_, const float* __restrict__ bn_,
    const float* __restrict__ Wni_, const float* __restrict__ Wnj_,
    unsigned short* __restrict__ hp, float* __restrict__ ni, float* __restrict__ nj) {
    __shared__ float hs[64][132];
    __shared__ float wb[2][8][192];
    int tid = threadIdx.x;
    int n0 = blockIdx.x * 64;

    float4 wreg[2];
    int wf0 = tid, wf1 = tid + 256;
    auto wload = [&](int s) {
#pragma unroll
        for (int u = 0; u < 2; u++) {
            int f = (u == 0) ? wf0 : wf1;
            if (f < 384) {
                int rr = f / 48, c = (f % 48) * 4;
                int dd = s * 8 + rr;
                const float* sp;
                if (c < 128) sp = Wn_ + (size_t)dd * 128 + c;
                else if (c < 160) sp = Wni_ + (size_t)dd * 32 + (c - 128);
                else sp = Wnj_ + (size_t)dd * 32 + (c - 160);
                wreg[u] = *(const float4*)sp;
            }
        }
    };
    auto wstore = [&](int buf) {
#pragma unroll
        for (int u = 0; u < 2; u++) {
            int f = (u == 0) ? wf0 : wf1;
            if (f < 384) {
                int rr = f / 48, c = (f % 48) * 4;
                *(float4*)&wb[buf][rr][c] = wreg[u];
            }
        }
    };

    wload(0);
#pragma unroll
    for (int k = 0; k < 8; k++) {
        int f = tid + k * 256;
        int r = f >> 5, c4 = f & 31;
        int row = n0 + r;
        if (row >= NN) row = NN - 1;
        float4 v = *(const float4*)(hin + (size_t)row * D + c4 * 4);
        if (APPLY_BN) {
            float4 sc = *(const float4*)(scsh + c4 * 4);
            float4 sh = *(const float4*)(scsh + 128 + c4 * 4);
            v.x = lrelu(v.x * sc.x + sh.x);
            v.y = lrelu(v.y * sc.y + sh.y);
            v.z = lrelu(v.z * sc.z + sh.z);
            v.w = lrelu(v.w * sc.w + sh.w);
        }
        *(float4*)(&hs[r][c4 * 4]) = v;
    }
    wstore(0);
    __syncthreads();

    int rg = tid >> 4;  // 0..15
    int cg = tid & 15;  // 0..15
    int pcol = 128 + (cg & 7) * 4 + ((cg < 8) ? 0 : 32);
    float4 bA = *(const float4*)(bn_ + cg * 4);
    float4 bB = *(const float4*)(bn_ + 64 + cg * 4);
    float4 accA[4], accB[4], accC[4];
#pragma unroll
    for (int r = 0; r < 4; r++) {
        accA[r] = bA;
        accB[r] = bB;
        accC[r] = make_float4(0.f, 0.f, 0.f, 0.f);
    }

#define FMA4(acc_, hv_, w_)                                     \
    (acc_).x += (hv_) * (w_).x; (acc_).y += (hv_) * (w_).y;     \
    (acc_).z += (hv_) * (w_).z; (acc_).w += (hv_) * (w_).w;

    for (int s = 0; s < 16; s++) {
        int cur = s & 1;
        if (s < 15) wload(s + 1);
#pragma unroll
        for (int dd = 0; dd < 8; dd++) {
            int d = s * 8 + dd;
            float h0 = hs[rg * 4 + 0][d];
            float h1 = hs[rg * 4 + 1][d];
            float h2 = hs[rg * 4 + 2][d];
            float h3 = hs[rg * 4 + 3][d];
            float4 wv0 = *(const float4*)&wb[cur][dd][cg * 4];
            float4 wv1 = *(const float4*)&wb[cur][dd][64 + cg * 4];
            float4 wv2 = *(const float4*)&wb[cur][dd][pcol];
            FMA4(accA[0], h0, wv0) FMA4(accA[1], h1, wv0)
            FMA4(accA[2], h2, wv0) FMA4(accA[3], h3, wv0)
            FMA4(accB[0], h0, wv1) FMA4(accB[1], h1, wv1)
            FMA4(accB[2], h2, wv1) FMA4(accB[3], h3, wv1)
            FMA4(accC[0], h0, wv2) FMA4(accC[1], h1, wv2)
            FMA4(accC[2], h2, wv2) FMA4(accC[3], h3, wv2)
        }
        __syncthreads();
        if (s < 15) {
            wstore((s + 1) & 1);
            __syncthreads();
        }
    }

    float* projOut = (cg < 8) ? ni : nj;
    int pc = (cg & 7) * 4;
#pragma unroll
    for (int r = 0; r < 4; r++) {
        int row = n0 + rg * 4 + r;
        if (row < NN) {
            ushort4 pa = make_ushort4(f2bf(accA[r].x), f2bf(accA[r].y), f2bf(accA[r].z),
                                      f2bf(accA[r].w));
            ushort4 pb = make_ushort4(f2bf(accB[r].x), f2bf(accB[r].y), f2bf(accB[r].z),
                                      f2bf(accB[r].w));
            *(ushort4*)(hp + (size_t)row * D + cg * 4) = pa;
            *(ushort4*)(hp + (size_t)row * D + 64 + cg * 4) = pb;
            *(float4*)(projOut + (size_t)row * HE + pc) = accC[r];
        }
    }
}

// ---------- layer-0 edge kernel (heads=1, e = scalar edge_p) ----------
__global__ __launch_bounds__(256) void k_edge0(
    const float* __restrict__ ep_s, const int* __restrict__ src_s,
    const int* __restrict__ dst_s, const float* __restrict__ ni,
    const float* __restrict__ nj, const float* __restrict__ Wfij,
    const float* __restrict__ attn, const float* __restrict__ ebias,
    unsigned short* __restrict__ fout, float* __restrict__ logits) {
    __shared__ float sw[HE], sa[HE], se[HE];
    int tid = threadIdx.x;
    if (tid < HE) {
        sw[tid] = Wfij[tid];
        sa[tid] = attn[tid];
        se[tid] = ebias[tid];
    }
    __syncthreads();
    int i = blockIdx.x * blockDim.x + tid;
    if (i >= NE) return;
    int sn = src_s[i], dn = dst_s[i];
    float p = ep_s[i];
    const float4* niv = (const float4*)(ni + (size_t)sn * HE);
    const float4* njv = (const float4*)(nj + (size_t)dn * HE);
    float acc[HE];
#pragma unroll
    for (int j = 0; j < 8; j++) {
        float4 a = niv[j];
        float4 b = njv[j];
        acc[4 * j + 0] = se[4 * j + 0] + p * sw[4 * j + 0] + a.x + b.x;
        acc[4 * j + 1] = se[4 * j + 1] + p * sw[4 * j + 1] + a.y + b.y;
        acc[4 * j + 2] = se[4 * j + 2] + p * sw[4 * j + 2] + a.z + b.z;
        acc[4 * j + 3] = se[4 * j + 3] + p * sw[4 * j + 3] + a.w + b.w;
    }
    float lg = 0.f;
#pragma unroll
    for (int k = 0; k < HE; k++) {
        acc[k] = lrelu(acc[k]);
        lg += acc[k] * sa[k];
    }
    uint4* fo = (uint4*)(fout + (size_t)i * HE);
#pragma unroll
    for (int j = 0; j < 4; j++) {
        uint4 v;
        v.x = pack2(acc[8 * j + 0], acc[8 * j + 1]);
        v.y = pack2(acc[8 * j + 2], acc[8 * j + 3]);
        v.z = pack2(acc[8 * j + 4], acc[8 * j + 5]);
        v.w = pack2(acc[8 * j + 6], acc[8 * j + 7]);
        fo[j] = v;
    }
    logits[i] = lg;
}

// ---------- deep edge kernel (heads=4); 1 edge/thread, plane-major logits ----------
template <int FIRST, int LAST>
__global__ __launch_bounds__(256) void k_edgeB(
    const unsigned short* __restrict__ e_in, const int* __restrict__ src_s,
    const int* __restrict__ dst_s, const float* __restrict__ ni,
    const float* __restrict__ nj, const float* __restrict__ Wfij,
    const float* __restrict__ attn, const float* __restrict__ ebias,
    const float* __restrict__ scsh,  // [256..287]=scaleE, [288..319]=shiftE (prev layer)
    unsigned short* __restrict__ fout, float* __restrict__ logits) {
    int i = blockIdx.x * blockDim.x + threadIdx.x;
    if (i >= NE) return;
    int sn = src_s[i], dn = dst_s[i];
    const float4* niv = (const float4*)(ni + (size_t)sn * HE);
    const float4* njv = (const float4*)(nj + (size_t)dn * HE);
    float acc[HE];
#pragma unroll
    for (int j = 0; j < 8; j++) {
        float4 a = niv[j];
        float4 b = njv[j];
        acc[4 * j + 0] = ebias[4 * j + 0] + a.x + b.x;
        acc[4 * j + 1] = ebias[4 * j + 1] + a.y + b.y;
        acc[4 * j + 2] = ebias[4 * j + 2] + a.z + b.z;
        acc[4 * j + 3] = ebias[4 * j + 3] + a.w + b.w;
    }
    const uint4* ein4 = (const uint4*)(e_in + (size_t)i * HE);
#pragma unroll
    for (int j = 0; j < 4; j++) {
        uint4 ev = ein4[j];
        float ec[8];
        unpk2(ev.x, ec[0], ec[1]);
        unpk2(ev.y, ec[2], ec[3]);
        unpk2(ev.z, ec[4], ec[5]);
        unpk2(ev.w, ec[6], ec[7]);
#pragma unroll
        for (int c = 0; c < 8; c++) {
            int de = 8 * j + c;
            float x = ec[c];
            if (!FIRST) x = lrelu(x * scsh[256 + de] + scsh[288 + de]);
            const float* wr = Wfij + (size_t)de * HE;
#pragma unroll
            for (int k = 0; k < HE; k++) acc[k] += x * wr[k];
        }
    }
#pragma unroll
    for (int k = 0; k < HE; k++) acc[k] = lrelu(acc[k]);
    if (!LAST) {
        uint4* fo = (uint4*)(fout + (size_t)i * HE);
#pragma unroll
        for (int j = 0; j < 4; j++) {
            uint4 v;
            v.x = pack2(acc[8 * j + 0], acc[8 * j + 1]);
            v.y = pack2(acc[8 * j + 2], acc[8 * j + 3]);
            v.z = pack2(acc[8 * j + 4], acc[8 * j + 5]);
            v.w = pack2(acc[8 * j + 6], acc[8 * j + 7]);
            fo[j] = v;
        }
    }
#pragma unroll
    for (int hh = 0; hh < HEADS; hh++) {
        float s = 0.f;
#pragma unroll
        for (int j = 0; j < 8; j++) s += acc[hh * 8 + j] * attn[hh * 8 + j];
        logits[(size_t)hh * NE + i] = s;
    }
}

// ---------- fused softmax-stats + aggregate: wave per node ----------
// phase 1: per-head m, 1/sum via 16-lane strided partial + shfl_xor tree (deterministic)
// phase 2: gather with w = exp(l-m)*inv inline
template <int H>
__global__ __launch_bounds__(256) void k_aggsm(const int* __restrict__ indptr,
                                               const int* __restrict__ src_s,
                                               const float* __restrict__ logits,
                                               const unsigned short* __restrict__ hp,
                                               float* __restrict__ hacc) {
    int n = blockIdx.x * 4 + (threadIdx.x >> 6);
    if (n >= NN) return;
    int lane = threadIdx.x & 63;
    int c2 = lane * 2;  // cols c2, c2+1
    int b = indptr[n], e = indptr[n + 1];
    int hh = (H == 1) ? 0 : (lane >> 4);
    const float* lp = logits + (size_t)hh * NE;
    const int stride = (H == 1) ? 64 : 16;
    int sub = (H == 1) ? lane : (lane & 15);
    float m = -1e30f;
    for (int i = b + sub; i < e; i += stride) m = fmaxf(m, lp[i]);
#pragma unroll
    for (int w = 32; w >= 1; w >>= 1)
        if (w < stride) m = fmaxf(m, __shfl_xor(m, w));
    float s = 0.f;
    for (int i = b + sub; i < e; i += stride) s += __expf(lp[i] - m);
#pragma unroll
    for (int w = 32; w >= 1; w >>= 1)
        if (w < stride) s += __shfl_xor(s, w);
    float inv = (e > b) ? 1.f / s : 0.f;
    float acc0 = 0.f, acc1 = 0.f;
#pragma unroll 4
    for (int i = b; i < e; i++) {
        float w = __expf(lp[i] - m) * inv;
        unsigned u = *(const unsigned*)(hp + (size_t)src_s[i] * D + c2);
        float x0, x1;
        unpk2(u, x0, x1);
        acc0 += w * x0;
        acc1 += w * x1;
    }
    *(float2*)(hacc + (size_t)n * D + c2) = make_float2(acc0, acc1);
}

// ---------- BN stats, merged H+E launch, deterministic per-block partials ----------
__global__ __launch_bounds__(256) void k_bnstats(const float* __restrict__ xh,
                                                 const unsigned short* __restrict__ xe,
                                                 float* __restrict__ partialH,
                                                 float* __restrict__ partialE) {
    int tid = threadIdx.x;
    if (blockIdx.x < SBH) {
        __shared__ float4 shs[256], shq[256];
        int c4 = (tid & 31) * 4;
        int r0 = tid >> 5;  // 0..7
        float4 s = make_float4(0.f, 0.f, 0.f, 0.f);
        float4 q = make_float4(0.f, 0.f, 0.f, 0.f);
        for (long r = (long)blockIdx.x * 8 + r0; r < NN; r += (long)SBH * 8) {
            float4 v = *(const float4*)(xh + r * D + c4);
            s.x += v.x; s.y += v.y; s.z += v.z; s.w += v.w;
            q.x += v.x * v.x; q.y += v.y * v.y; q.z += v.z * v.z; q.w += v.w * v.w;
        }
        shs[tid] = s;
        shq[tid] = q;
        __syncthreads();
        for (int st = 128; st >= 32; st >>= 1) {
            if (tid < st) {
                float4 a = shs[tid], b = shs[tid + st];
                a.x += b.x; a.y += b.y; a.z += b.z; a.w += b.w;
                shs[tid] = a;
                float4 c = shq[tid], d = shq[tid + st];
                c.x += d.x; c.y += d.y; c.z += d.z; c.w += d.w;
                shq[tid] = c;
            }
            __syncthreads();
        }
        if (tid < 32) {
            *(float4*)&partialH[(size_t)blockIdx.x * 256 + 4 * tid] = shs[tid];
            *(float4*)&partialH[(size_t)blockIdx.x * 256 + 128 + 4 * tid] = shq[tid];
        }
    } else {
        __shared__ float shs0[256], shs1[256], shq0[256], shq1[256];
        int blk = blockIdx.x - SBH;
        int d = tid & 15;
        int r0 = tid >> 4;  // 0..15
        float s0 = 0.f, s1 = 0.f, q0 = 0.f, q1 = 0.f;
        for (long r = (long)blk * 16 + r0; r < NE; r += (long)SBE * 16) {
            unsigned u = *(const unsigned*)(xe + r * HE + 2 * d);
            float a, b;
            unpk2(u, a, b);
            s0 += a; s1 += b;
            q0 += a * a; q1 += b * b;
        }
        shs0[tid] = s0; shs1[tid] = s1;
        shq0[tid] = q0; shq1[tid] = q1;
        __syncthreads();
        for (int st = 128; st >= 16; st >>= 1) {
            if (tid < st) {
                shs0[tid] += shs0[tid + st];
                shs1[tid] += shs1[tid + st];
                shq0[tid] += shq0[tid + st];
                shq1[tid] += shq1[tid + st];
            }
            __syncthreads();
        }
        if (tid < 16) {
            partialE[(size_t)blk * 64 + 2 * tid] = shs0[tid];
            partialE[(size_t)blk * 64 + 2 * tid + 1] = shs1[tid];
            partialE[(size_t)blk * 64 + 32 + 2 * tid] = shq0[tid];
            partialE[(size_t)blk * 64 + 32 + 2 * tid + 1] = shq1[tid];
        }
    }
}

// ---------- BN scale/shift prep: parallel deterministic tree reduce ----------
__global__ __launch_bounds__(256) void k_bnprep(const float* __restrict__ partialH,
                                                const float* __restrict__ gH,
                                                const float* __restrict__ bH,
                                                const float* __restrict__ partialE,
                                                const float* __restrict__ gE,
                                                const float* __restrict__ bE,
                                                float* __restrict__ scsh, int doE) {
    __shared__ float sh[512];
    int f = blockIdx.x;
    int tid = threadIdx.x;
    if (f < 128) {
        float s = 0.f, s2 = 0.f;
        for (int b = tid; b < SBH; b += 256) {
            s += partialH[(size_t)b * 256 + f];
            s2 += partialH[(size_t)b * 256 + 128 + f];
        }
        sh[tid] = s;
        sh[256 + tid] = s2;
        __syncthreads();
        for (int st = 128; st >= 1; st >>= 1) {
            if (tid < st) {
                sh[tid] += sh[tid + st];
                sh[256 + tid] += sh[256 + tid + st];
            }
            __syncthreads();
        }
        if (tid == 0) {
            float mu = sh[0] * (1.f / NN);
            float var = sh[256] * (1.f / NN) - mu * mu;
            float sc = rsqrtf(var + EPSV) * gH[f];
            scsh[f] = sc;
            scsh[128 + f] = bH[f] - mu * sc;
        }
    } else {
        if (!doE) return;
        int k = f - 128;
        float s = 0.f, s2 = 0.f;
        for (int b = tid; b < SBE; b += 256) {
            s += partialE[(size_t)b * 64 + k];
            s2 += partialE[(size_t)b * 64 + 32 + k];
        }
        sh[tid] = s;
        sh[256 + tid] = s2;
        __syncthreads();
        for (int st = 128; st >= 1; st >>= 1) {
            if (tid < st) {
                sh[tid] += sh[tid + st];
                sh[256 + tid] += sh[256 + tid + st];
            }
            __syncthreads();
        }
        if (tid == 0) {
            float mu = sh[0] * (1.f / NE);
            float var = sh[256] * (1.f / NE) - mu * mu;
            float sc = rsqrtf(var + EPSV) * gE[k];
            scsh[256 + k] = sc;
            scsh[288 + k] = bE[k] - mu * sc;
        }
    }
}

// ---------- out = lrelu(BN(h)) @ Wfc + bfc ----------
__global__ void k_out(const float* __restrict__ h, const float* __restrict__ scsh,
                      const float* __restrict__ Wfc, const float* __restrict__ bfc,
                      float* __restrict__ out) {
    int n = blockIdx.x * blockDim.x + threadIdx.x;
    if (n >= NN) return;
    const float* hr = h + (size_t)n * D;
    float s = bfc[0];
    for (int d = 0; d < D; d++) {
        float v = lrelu(hr[d] * scsh[d] + scsh[128 + d]);
        s += v * Wfc[d];
    }
    out[n] = s;
}

extern "C" void kernel_launch(void* const* d_in, const int* in_sizes, int n_in,
                              void* d_out, int out_size, void* d_ws, size_t ws_size,
                              hipStream_t stream) {
    const int* seq = (const int*)d_in[0];
    const int* sec = (const int*)d_in[1];
    const float* edge_p = (const float*)d_in[2];
    const int* src = (const int*)d_in[3];
    const int* dst = (const int*)d_in[4];
    const float* Wseq = (const float*)d_in[5];
    const float* Wsec = (const float*)d_in[6];
    const float* W0_node = (const float*)d_in[7];
    const float* b0_node = (const float*)d_in[8];
    const float* W0_ni = (const float*)d_in[9];
    const float* W0_fij = (const float*)d_in[10];
    const float* W0_nj = (const float*)d_in[11];
    const float* attn0 = (const float*)d_in[12];
    const float* ebias0 = (const float*)d_in[13];
    const float* Wn = (const float*)d_in[14];
    const float* bn = (const float*)d_in[15];
    const float* Wni = (const float*)d_in[16];
    const float* Wfij = (const float*)d_in[17];
    const float* Wnj = (const float*)d_in[18];
    const float* attnB = (const float*)d_in[19];
    const float* ebiasB = (const float*)d_in[20];
    const float* gn = (const float*)d_in[21];
    const float* betan = (const float*)d_in[22];
    const float* ge = (const float*)d_in[23];
    const float* betae = (const float*)d_in[24];
    const float* Wfc = (const float*)d_in[25];
    const float* bfc = (const float*)d_in[26];

    char* p = (char*)d_ws;
    auto alloc = [&](size_t bytes) -> char* {
        char* r = p;
        p += (bytes + 255) & ~(size_t)255;
        return r;
    };
    float* hA = (float*)alloc((size_t)NN * D * 4);
    float* hB = (float*)alloc((size_t)NN * D * 4);
    unsigned short* hp = (unsigned short*)alloc((size_t)NN * D * 2);      // bf16
    unsigned short* ebuf = (unsigned short*)alloc((size_t)NE * HE * 2);   // bf16, in-place
    float* logits = (float*)alloc((size_t)NE * HEADS * 4);                // [H][NE] planes
    float* ni = (float*)alloc((size_t)NN * HE * 4);
    float* nj = (float*)alloc((size_t)NN * HE * 4);
    int* esort = (int*)alloc((size_t)NE * 4);
    int* src_s = (int*)alloc((size_t)NE * 4);
    int* dst_s = (int*)alloc((size_t)NE * 4);
    float* ep_s = (float*)alloc((size_t)NE * 4);
    int* cnt = (int*)alloc((size_t)NN * 4);
    int* cursor = (int*)alloc((size_t)NN * 4);
    int* indptr = (int*)alloc((size_t)(NN + 1) * 4);
    int* bsum = (int*)alloc(256 * 4);
    int* bscan = (int*)alloc(256 * 4);
    float* partialH = (float*)alloc((size_t)SBH * 256 * 4);
    float* partialE = (float*)alloc((size_t)SBE * 64 * 4);
    float* scsh0 = (float*)alloc(320 * 4);
    float* scsh1 = (float*)alloc(320 * 4);

    const int EB = (NE + 255) / 256;   // 3125
    const int NB64 = (NN + 63) / 64;   // 782

    // CSR build + deterministic segment order + permuted edge arrays
    hipMemsetAsync(cnt, 0, (size_t)NN * 4, stream);
    hipMemsetAsync(cursor, 0, (size_t)NN * 4, stream);
    k_init_h<<<NN, 128, 0, stream>>>(seq, sec, Wseq, Wsec, hB);
    k_count<<<EB, 256, 0, stream>>>(dst, cnt);
    k_bsum<<<256, 256, 0, stream>>>(cnt, bsum);
    k_bscan<<<1, 256, 0, stream>>>(bsum, bscan, indptr);
    k_bwrite<<<256, 256, 0, stream>>>(cnt, bscan, indptr);
    k_scatter<<<EB, 256, 0, stream>>>(dst, indptr, cursor, esort);
    k_sortseg<<<(NN + 255) / 256, 256, 0, stream>>>(indptr, esort);
    k_permute<<<EB, 256, 0, stream>>>(esort, src, dst, edge_p, src_s, dst_s, ep_s);

    // ---- layer 0 (heads = 1), no BN ----
    k_node<0><<<NB64, 256, 0, stream>>>(hB, scsh0, W0_node, b0_node, W0_ni, W0_nj, hp, ni, nj);
    k_edge0<<<EB, 256, 0, stream>>>(ep_s, src_s, dst_s, ni, nj, W0_fij, attn0, ebias0, ebuf,
                                    logits);
    k_aggsm<1><<<(NN + 3) / 4, 256, 0, stream>>>(indptr, src_s, logits, hp, hA);

    // ---- deep layers (input hA for l=0; ping-pong) ----
    for (int l = 0; l < DEPTH; l++) {
        const float* Wn_l = Wn + (size_t)l * D * D;
        const float* bn_l = bn + (size_t)l * D;
        const float* Wni_l = Wni + (size_t)l * D * HE;
        const float* Wfij_l = Wfij + (size_t)l * HE * HE;
        const float* Wnj_l = Wnj + (size_t)l * D * HE;
        const float* attn_l = attnB + (size_t)l * HE;
        const float* eb_l = ebiasB + (size_t)l * HE;
        float* scshPrev = (l & 1) ? scsh0 : scsh1;
        float* scshCur = (l & 1) ? scsh1 : scsh0;
        float* hIn = (l & 1) ? hB : hA;
        float* hOut = (l & 1) ? hA : hB;
        int doE = (l < DEPTH - 1) ? 1 : 0;

        if (l == 0)
            k_node<0><<<NB64, 256, 0, stream>>>(hIn, scshPrev, Wn_l, bn_l, Wni_l, Wnj_l, hp,
                                                ni, nj);
        else
            k_node<1><<<NB64, 256, 0, stream>>>(hIn, scshPrev, Wn_l, bn_l, Wni_l, Wnj_l, hp,
                                                ni, nj);

        if (l == 0)
            k_edgeB<1, 0><<<EB, 256, 0, stream>>>(ebuf, src_s, dst_s, ni, nj, Wfij_l, attn_l,
                                                  eb_l, scshPrev, ebuf, logits);
        else if (l == DEPTH - 1)
            k_edgeB<0, 1><<<EB, 256, 0, stream>>>(ebuf, src_s, dst_s, ni, nj, Wfij_l, attn_l,
                                                  eb_l, scshPrev, ebuf, logits);
        else
            k_edgeB<0, 0><<<EB, 256, 0, stream>>>(ebuf, src_s, dst_s, ni, nj, Wfij_l, attn_l,
                                                  eb_l, scshPrev, ebuf, logits);
        k_aggsm<HEADS><<<(NN + 3) / 4, 256, 0, stream>>>(indptr, src_s, logits, hp, hOut);

        k_bnstats<<<SBH + (doE ? SBE : 0), 256, 0, stream>>>(hOut, ebuf, partialH, partialE);
        k_bnprep<<<160, 256, 0, stream>>>(partialH, gn + (size_t)l * D, betan + (size_t)l * D,
                                          partialE, ge + (size_t)l * HE, betae + (size_t)l * HE,
                                          scshCur, doE);
    }

    // final h is in hA (l=7 wrote hOut=hA); BN of layer 7 is in scsh1
    k_out<<<(NN + 255) / 256, 256, 0, stream>>>(hA, scsh1, Wfc, bfc, (float*)d_out);
}